// Round 4
// baseline (184.116 us; speedup 1.0000x reference)
//
#include <hip/hip_runtime.h>
#include <stdint.h>

// Problem constants: bs=16, Q=1024, P=8, D=256, Cin=64, H=W=128, Cout=256.

typedef __attribute__((ext_vector_type(8))) short short8;   // 8 bf16 (4 VGPR)
typedef __attribute__((ext_vector_type(4))) float f32x4;    // MFMA acc

__device__ __forceinline__ unsigned short f2bf(float f) {
  union { float f; unsigned int u; } v; v.f = f;
  unsigned int r = (v.u + 0x7FFFu + ((v.u >> 16) & 1u)) >> 16;  // RNE
  return (unsigned short)r;
}
__device__ __forceinline__ float bf2f(unsigned short h) {
  union { unsigned int u; float f; } v; v.u = ((unsigned int)h) << 16;
  return v.f;
}

// async global->LDS, 16B per lane; LDS dest wave-uniform (HW adds lane*16),
// global src per-lane.
__device__ __forceinline__ void gload_lds16(const void* g, void* l) {
  __builtin_amdgcn_global_load_lds(
      (const __attribute__((address_space(1))) unsigned int*)g,
      (__attribute__((address_space(3))) unsigned int*)l, 16, 0, 0);
}

// ---------------------------------------------------------------------------
// K1: bev (16,64,128,128) f32 NCHW -> bev_nhwc (16,128,128,64) bf16 (unchanged)
// ---------------------------------------------------------------------------
__global__ __launch_bounds__(256) void k1_transpose(const float* __restrict__ bev,
                                                    unsigned short* __restrict__ nhwc) {
  __shared__ __align__(16) float lds[64 * 32 * 4];
  const int b = blockIdx.x >> 7, y = blockIdx.x & 127;
  const int t = threadIdx.x;
  const float* src = bev + (size_t)(b * 64) * 16384 + y * 128;
#pragma unroll
  for (int k = 0; k < 8; ++k) {
    int chunk = k * 256 + t;
    int ic = chunk >> 5, xq = chunk & 31;
    float4 v = *(const float4*)(src + ic * 16384 + xq * 4);
    int slot = xq ^ (ic >> 3);
    *(float4*)&lds[(ic * 32 + slot) * 4] = v;
  }
  __syncthreads();
  unsigned short* dst = nhwc + (size_t)blockIdx.x * 8192;
#pragma unroll
  for (int k = 0; k < 4; ++k) {
    int co = k * 256 + t;
    int x = co >> 3, icg = co & 7;
    int slot = (x >> 2) ^ icg;
    int w = x & 3;
    uint4 u;
    unsigned int* up = (unsigned int*)&u;
#pragma unroll
    for (int jj = 0; jj < 4; ++jj) {
      float v0 = lds[((icg * 8 + 2 * jj) * 32 + slot) * 4 + w];
      float v1 = lds[((icg * 8 + 2 * jj + 1) * 32 + slot) * 4 + w];
      up[jj] = (unsigned int)f2bf(v0) | ((unsigned int)f2bf(v1) << 16);
    }
    *(uint4*)(dst + x * 64 + icg * 8) = u;
  }
}

// ---------------------------------------------------------------------------
// K1b: pack weights (unchanged layouts)
//   wconv[o][gg8][oc256][j8] = conv_w[oc][gg*8+j][o/3][o%3]
//   wout [cg32][d256][j8]    = out_w[d][cg*8+j]
// ---------------------------------------------------------------------------
__global__ __launch_bounds__(256) void k1b_pack(const float* __restrict__ conv_w,
                                                const float* __restrict__ out_w,
                                                unsigned short* __restrict__ wconv,
                                                unsigned short* __restrict__ wout,
                                                float* __restrict__ zp) {
  const int tid = blockIdx.x * 256 + threadIdx.x;
  for (int idx = tid; idx < 9 * 8 * 256 * 8; idx += 16384) {
    int j = idx & 7, oc = (idx >> 3) & 255, g = (idx >> 11) & 7, o = idx >> 14;
    wconv[idx] = f2bf(conv_w[(oc * 64 + g * 8 + j) * 9 + o]);
  }
  for (int idx = tid; idx < 32 * 256 * 8; idx += 16384) {
    int j = idx & 7, d = (idx >> 3) & 255, g = idx >> 11;
    wout[idx] = f2bf(out_w[d * 256 + g * 8 + j]);
  }
  if (tid < 64) zp[tid] = 0.0f;
}

// ---------------------------------------------------------------------------
// K2 v4: 3x3 conv + bias + relu, implicit GEMM, D[oc][pix] = W[oc][k]·In[k][pix]
// block = (b, row-pair): 256 pix x 256 oc, 256 threads = 4 WAVES of 128oc x128pix
// (2x2 wave grid, 1 wave/SIMD, acc[8][8]=256 VGPR, __launch_bounds__(256,1)).
// Per K-step per CU: LDS reads 64KB (~753cyc) < MFMA 1033cyc -> MFMA-bound.
// Register-level pipeline: step s issues weight stage(s+3) (4-deep ring,
// counted vmcnt(4)), ds_reads frags(s+1) into the idle buffer (aN/bN), runs
// 64 MFMA on the current buffer (aC/bC). Reads hide under the MFMA burst.
// Publish-one-early: barrier at end of step s publishes slot s+2, so frags
// (s+1) are readable during step s.  Slot k: staged @k-3, published @k-2,
// read @k-1, consumed @k, rewritten @k+1.
// ---------------------------------------------------------------------------
#define K2_WOFF 66560

#define K2_STAGE(s1) do {                                                     \
    const unsigned short* wsrc_ = wconv + (size_t)(s1) * 8192;                \
    char* wdst_ = smem + K2_WOFF + ((s1) & 3) * 16384;                        \
    _Pragma("unroll")                                                         \
    for (int j_ = 0; j_ < 4; ++j_)                                            \
      gload_lds16(wsrc_ + (size_t)((wid * 4 + j_) * 64 + lane) * 8,           \
                  wdst_ + (wid * 4 + j_) * 1024);                             \
  } while (0)

#define K2_READ(sr, A, B) do {                                                \
    const short8* wb_ = (const short8*)(smem + K2_WOFF + ((sr) & 3) * 16384); \
    _Pragma("unroll")                                                         \
    for (int ocf_ = 0; ocf_ < 8; ++ocf_) A[ocf_] = wb_[aoff + ocf_ * 16];     \
    const int o_ = (sr) >> 1, ich_ = (sr) & 1;                                \
    const int dyr_ = o_ / 3, dx_ = o_ - dyr_ * 3 - 1;                         \
    const int cb_ = ((rh + dyr_) * 8 + ich_ * 4 + g) * 130 + 1 + dx_ + l15;   \
    _Pragma("unroll")                                                         \
    for (int pf_ = 0; pf_ < 8; ++pf_) B[pf_] = lin[cb_ + pf_ * 16];           \
  } while (0)

#define K2_MFMA(A, B) do {                                                    \
    __builtin_amdgcn_s_setprio(1);                                            \
    _Pragma("unroll")                                                         \
    for (int ocf_ = 0; ocf_ < 8; ++ocf_)                                      \
      _Pragma("unroll")                                                       \
      for (int pf_ = 0; pf_ < 8; ++pf_)                                       \
        acc[ocf_][pf_] = __builtin_amdgcn_mfma_f32_16x16x32_bf16(             \
            A[ocf_], B[pf_], acc[ocf_][pf_], 0, 0, 0);                        \
    __builtin_amdgcn_s_setprio(0);                                            \
  } while (0)

__global__ __launch_bounds__(256, 1) void k2_conv(const unsigned short* __restrict__ nhwc,
                                                  const unsigned short* __restrict__ wconv,
                                                  const float* __restrict__ conv_b,
                                                  const float* __restrict__ zp,
                                                  unsigned short* __restrict__ value) {
  __shared__ __align__(16) char smem[132096];   // 66560 input + 4*16384 weights
  const short8* lin = (const short8*)smem;
  const int bid = blockIdx.x;
  const int swz = (bid & 7) * 128 + (bid >> 3);    // XCD swizzle: 2 images/XCD
  const int b = swz >> 6, yp = swz & 63;
  const int y0 = yp * 2;
  const int t = threadIdx.x, wid = t >> 6, lane = t & 63;
  const int wo = wid >> 1, rh = wid & 1;           // oc-half, row-in-pair
  const int g = lane >> 4, l15 = lane & 15;
  const int aoff = g * 256 + wo * 128 + l15;       // A-frag chunk base in slot

  // ---- prologue: stage input rows y0-1..y0+2 (4160 chunks = 65 issues) ----
  const unsigned short* bevb = nhwc + (size_t)b * (128 * 128 * 64);
  for (int i = wid; i < 65; i += 4) {
    const int chunk = i * 64 + lane;
    const int ridx = chunk / 1040;
    const int rem = chunk - ridx * 1040;
    const int icg = rem / 130;
    const int c = rem - icg * 130;
    const int yy = y0 - 1 + ridx, xx = c - 1;
    const void* src = (yy >= 0 && yy < 128 && xx >= 0 && xx < 128)
                          ? (const void*)(bevb + ((yy * 128 + xx) * 64 + icg * 8))
                          : (const void*)zp;
    gload_lds16(src, smem + i * 1024);
  }
  // stage weight ring slots 0..2
  K2_STAGE(0);
  K2_STAGE(1);
  K2_STAGE(2);
  // input + slots 0,1 published (slot 2's 4 loads may stay in flight)
  asm volatile("s_waitcnt vmcnt(4)" ::: "memory");
  __builtin_amdgcn_s_barrier();

  const f32x4 z4 = {0.f, 0.f, 0.f, 0.f};
  f32x4 acc[8][8];
#pragma unroll
  for (int i = 0; i < 8; ++i)
#pragma unroll
    for (int j = 0; j < 8; ++j) acc[i][j] = z4;

  short8 aC[8], bC[8], aN[8], bN[8];
  K2_READ(0, aC, bC);                      // frags(0) from slot 0 + input

  // ---- main loop: steps 0..13 (uniform), then peeled 14..17 ----
  for (int it = 0; it < 7; ++it) {
    const int s0 = 2 * it, s1 = 2 * it + 1;
    // even step s0: stage(s0+3), read frags(s0+1)->N, mfma on C
    K2_STAGE(s0 + 3);
    K2_READ(s0 + 1, aN, bN);
    K2_MFMA(aC, bC);
    asm volatile("s_waitcnt vmcnt(4)" ::: "memory");   // publish slot s0+2
    __builtin_amdgcn_s_barrier();
    // odd step s1: stage(s1+3), read frags(s1+1)->C, mfma on N
    K2_STAGE(s1 + 3);
    K2_READ(s1 + 1, aC, bC);
    K2_MFMA(aN, bN);
    asm volatile("s_waitcnt vmcnt(4)" ::: "memory");   // publish slot s1+2
    __builtin_amdgcn_s_barrier();
  }
  // s=14: stage(17), read(15)->N, mfma(C=14); publish 16
  K2_STAGE(17);
  K2_READ(15, aN, bN);
  K2_MFMA(aC, bC);
  asm volatile("s_waitcnt vmcnt(4)" ::: "memory");
  __builtin_amdgcn_s_barrier();
  // s=15: read(16)->C, mfma(N=15); publish 17 (drain)
  K2_READ(16, aC, bC);
  K2_MFMA(aN, bN);
  asm volatile("s_waitcnt vmcnt(0)" ::: "memory");
  __builtin_amdgcn_s_barrier();
  // s=16: read(17)->N, mfma(C=16)
  K2_READ(17, aN, bN);
  K2_MFMA(aC, bC);
  // s=17: mfma(N=17)
  K2_MFMA(aN, bN);

  // ---- epilogue: bias + relu -> direct ushort4 stores (4 consecutive oc) ----
  const int y = y0 + rh;
  unsigned short* vrow = value + (((size_t)(b * 128 + y) * 128 + l15) * 256);
#pragma unroll
  for (int ocf = 0; ocf < 8; ++ocf) {
    const int ocb = wo * 128 + ocf * 16 + g * 4;
    const float4 cb4 = *(const float4*)(conv_b + ocb);
#pragma unroll
    for (int pf = 0; pf < 8; ++pf) {
      ushort4 ov;
      float v0 = acc[ocf][pf][0] + cb4.x; ov.x = f2bf(v0 > 0.f ? v0 : 0.f);
      float v1 = acc[ocf][pf][1] + cb4.y; ov.y = f2bf(v1 > 0.f ? v1 : 0.f);
      float v2 = acc[ocf][pf][2] + cb4.z; ov.z = f2bf(v2 > 0.f ? v2 : 0.f);
      float v3 = acc[ocf][pf][3] + cb4.w; ov.w = f2bf(v3 > 0.f ? v3 : 0.f);
      *(ushort4*)(vrow + (size_t)pf * 16 * 256 + ocb) = ov;
    }
  }
}

// ---------------------------------------------------------------------------
// K3: per-query softmax + bilinear grid-sample + P-weighted sum (unchanged)
// ---------------------------------------------------------------------------
__global__ __launch_bounds__(256) void k3_sample(const float* __restrict__ queries,
                                                 const float* __restrict__ traj,
                                                 const float* __restrict__ attn_w,
                                                 const float* __restrict__ attn_b,
                                                 const unsigned short* __restrict__ value,
                                                 unsigned short* __restrict__ S) {
  const int wid = threadIdx.x >> 6, lane = threadIdx.x & 63;
  const int qg = blockIdx.x * 4 + wid;
  const int b = qg >> 10;
  const float4 qv = ((const float4*)queries)[qg * 64 + lane];
  float a[8];
#pragma unroll
  for (int p = 0; p < 8; ++p) {
    float4 wv = ((const float4*)attn_w)[p * 64 + lane];
    float d = qv.x * wv.x + qv.y * wv.y + qv.z * wv.z + qv.w * wv.w;
#pragma unroll
    for (int off = 32; off >= 1; off >>= 1) d += __shfl_xor(d, off);
    a[p] = d + attn_b[p];
  }
  float mx = a[0];
#pragma unroll
  for (int p = 1; p < 8; ++p) mx = fmaxf(mx, a[p]);
  float ssum = 0.f;
#pragma unroll
  for (int p = 0; p < 8; ++p) { a[p] = __expf(a[p] - mx); ssum += a[p]; }
  const float inv = 1.f / ssum;

  float acc0 = 0.f, acc1 = 0.f, acc2 = 0.f, acc3 = 0.f;
  const unsigned short* vb = value + (size_t)b * (128 * 128 * 256);
  const int coff = lane * 4;
#pragma unroll
  for (int p = 0; p < 8; ++p) {
    const float ty = traj[(qg * 8 + p) * 2 + 0];
    const float tx = traj[(qg * 8 + p) * 2 + 1];
    const float fx = (tx * 0.03125f + 1.f) * 64.f - 0.5f;
    const float fy = (ty * 0.03125f + 1.f) * 64.f - 0.5f;
    const float fx0 = floorf(fx), fy0 = floorf(fy);
    const int ix0 = (int)fx0, iy0 = (int)fy0;
    const float wx1 = fx - fx0, wx0 = 1.f - wx1;
    const float wy1 = fy - fy0, wy0 = 1.f - wy1;
    const float ap = a[p] * inv;
    const float cw[4] = {wx0 * wy0 * ap, wx1 * wy0 * ap, wx0 * wy1 * ap, wx1 * wy1 * ap};
    const int cx[4] = {ix0, ix0 + 1, ix0, ix0 + 1};
    const int cy[4] = {iy0, iy0, iy0 + 1, iy0 + 1};
#pragma unroll
    for (int cc = 0; cc < 4; ++cc) {
      if (cx[cc] >= 0 && cx[cc] < 128 && cy[cc] >= 0 && cy[cc] < 128) {
        const ushort4 v = *(const ushort4*)(vb + (cy[cc] * 128 + cx[cc]) * 256 + coff);
        acc0 += cw[cc] * bf2f(v.x);
        acc1 += cw[cc] * bf2f(v.y);
        acc2 += cw[cc] * bf2f(v.z);
        acc3 += cw[cc] * bf2f(v.w);
      }
    }
  }
  ushort4 o;
  o.x = f2bf(acc0); o.y = f2bf(acc1); o.z = f2bf(acc2); o.w = f2bf(acc3);
  *(ushort4*)(S + (size_t)qg * 256 + coff) = o;
}

// ---------------------------------------------------------------------------
// K4 v2: out[q][d] = S[q][:] . out_w[d][:] + out_b[d] + queries[q][d]
// (unchanged)
// ---------------------------------------------------------------------------
__global__ __launch_bounds__(256, 2) void k4_proj(const unsigned short* __restrict__ S,
                                                  const unsigned short* __restrict__ wout,
                                                  const float* __restrict__ out_b,
                                                  const float* __restrict__ queries,
                                                  float* __restrict__ out) {
  __shared__ __align__(16) char smem[16384];     // 2 x 512 chunks [gg4][q128]
  const short8* lds8 = (const short8*)smem;
  const short8* wp8 = (const short8*)wout;
  const int t = threadIdx.x, wid = t >> 6, lane = t & 63;
  const int wo = wid >> 1, wq = wid & 1;         // d-half, q-half
  const int q0 = blockIdx.x * 128;
  const int g = lane >> 4, l15 = lane & 15;
  const f32x4 z4 = {0.f, 0.f, 0.f, 0.f};
  f32x4 acc[8][4];
#pragma unroll
  for (int i = 0; i < 8; ++i)
#pragma unroll
    for (int j = 0; j < 4; ++j) acc[i][j] = z4;

  // stage ks=0
#pragma unroll
  for (int ii = 0; ii < 2; ++ii) {
    const int chunk = wid * 128 + ii * 64 + lane;
    const int gg = chunk >> 7, q = chunk & 127;
    gload_lds16(S + ((size_t)(q0 + q) * 256 + gg * 8), smem + wid * 2048 + ii * 1024);
  }
  __syncthreads();

#pragma unroll
  for (int ks = 0; ks < 8; ++ks) {
    if (ks < 7) {
      const int k1 = ks + 1;
#pragma unroll
      for (int ii = 0; ii < 2; ++ii) {
        const int chunk = wid * 128 + ii * 64 + lane;
        const int gg = chunk >> 7, q = chunk & 127;
        gload_lds16(S + ((size_t)(q0 + q) * 256 + k1 * 32 + gg * 8),
                    smem + ((k1 & 1) ? 8192 : 0) + wid * 2048 + ii * 1024);
      }
    }
    short8 af[8];
#pragma unroll
    for (int df = 0; df < 8; ++df)
      af[df] = wp8[(ks * 4 + g) * 256 + wo * 128 + df * 16 + l15];
    short8 bf[4];
    const short8* sb = lds8 + ((ks & 1) ? 512 : 0);
#pragma unroll
    for (int qf = 0; qf < 4; ++qf) bf[qf] = sb[g * 128 + wq * 64 + qf * 16 + l15];
    __builtin_amdgcn_s_setprio(1);
#pragma unroll
    for (int df = 0; df < 8; ++df)
#pragma unroll
      for (int qf = 0; qf < 4; ++qf)
        acc[df][qf] = __builtin_amdgcn_mfma_f32_16x16x32_bf16(af[df], bf[qf], acc[df][qf], 0, 0, 0);
    __builtin_amdgcn_s_setprio(0);
    __syncthreads();
  }

#pragma unroll
  for (int df = 0; df < 8; ++df) {
    const int db = wo * 128 + df * 16 + g * 4;
    const float4 ob4 = *(const float4*)(out_b + db);
#pragma unroll
    for (int qf = 0; qf < 4; ++qf) {
      const int q = q0 + wq * 64 + qf * 16 + l15;
      const float4 qv = *(const float4*)(queries + (size_t)q * 256 + db);
      float4 ov;
      ov.x = acc[df][qf][0] + ob4.x + qv.x;
      ov.y = acc[df][qf][1] + ob4.y + qv.y;
      ov.z = acc[df][qf][2] + ob4.z + qv.z;
      ov.w = acc[df][qf][3] + ob4.w + qv.w;
      *(float4*)(out + (size_t)q * 256 + db) = ov;
    }
  }
}

// ---------------------------------------------------------------------------
extern "C" void kernel_launch(void* const* d_in, const int* in_sizes, int n_in,
                              void* d_out, int out_size, void* d_ws, size_t ws_size,
                              hipStream_t stream) {
  const float* queries = (const float*)d_in[0];
  const float* traj    = (const float*)d_in[1];
  const float* bev     = (const float*)d_in[2];
  const float* attn_w  = (const float*)d_in[4];
  const float* attn_b  = (const float*)d_in[5];
  const float* conv_w  = (const float*)d_in[6];
  const float* conv_b  = (const float*)d_in[7];
  const float* out_w   = (const float*)d_in[8];
  const float* out_b   = (const float*)d_in[9];
  float* out = (float*)d_out;

  char* ws = (char*)d_ws;
  unsigned short* bev_nhwc = (unsigned short*)(ws);               //  33,554,432 B
  unsigned short* value    = (unsigned short*)(ws + 33554432);    // 134,217,728 B
  unsigned short* wconv    = (unsigned short*)(ws + 167772160);   //     294,912 B
  unsigned short* wout     = (unsigned short*)(ws + 168067072);   //     131,072 B
  unsigned short* Sbuf     = (unsigned short*)(ws + 168198144);   //   8,388,608 B
  float*          zp       = (float*)(ws + 176586752);            //         256 B

  k1_transpose<<<2048, 256, 0, stream>>>(bev, bev_nhwc);
  k1b_pack<<<64, 256, 0, stream>>>(conv_w, out_w, wconv, wout, zp);
  k2_conv<<<1024, 256, 0, stream>>>(bev_nhwc, wconv, conv_b, zp, value);
  k3_sample<<<4096, 256, 0, stream>>>(queries, traj, attn_w, attn_b, value, Sbuf);
  k4_proj<<<128, 256, 0, stream>>>(Sbuf, wout, out_b, queries, out);
}

// Round 5
// 182.299 us; speedup vs baseline: 1.0100x; 1.0100x over previous
//
#include <hip/hip_runtime.h>
#include <stdint.h>

// Problem constants: bs=16, Q=1024, P=8, D=256, Cin=64, H=W=128, Cout=256.

typedef __attribute__((ext_vector_type(8))) short short8;   // 8 bf16 (4 VGPR)
typedef __attribute__((ext_vector_type(4))) float f32x4;    // MFMA acc

__device__ __forceinline__ unsigned short f2bf(float f) {
  union { float f; unsigned int u; } v; v.f = f;
  unsigned int r = (v.u + 0x7FFFu + ((v.u >> 16) & 1u)) >> 16;  // RNE
  return (unsigned short)r;
}
__device__ __forceinline__ float bf2f(unsigned short h) {
  union { unsigned int u; float f; } v; v.u = ((unsigned int)h) << 16;
  return v.f;
}

// async global->LDS, 16B per lane; LDS dest wave-uniform (HW adds lane*16),
// global src per-lane.
__device__ __forceinline__ void gload_lds16(const void* g, void* l) {
  __builtin_amdgcn_global_load_lds(
      (const __attribute__((address_space(1))) unsigned int*)g,
      (__attribute__((address_space(3))) unsigned int*)l, 16, 0, 0);
}

// ---------------------------------------------------------------------------
// K1: bev (16,64,128,128) f32 NCHW -> bev_nhwc (16,128,128,64) bf16 (unchanged)
// ---------------------------------------------------------------------------
__global__ __launch_bounds__(256) void k1_transpose(const float* __restrict__ bev,
                                                    unsigned short* __restrict__ nhwc) {
  __shared__ __align__(16) float lds[64 * 32 * 4];
  const int b = blockIdx.x >> 7, y = blockIdx.x & 127;
  const int t = threadIdx.x;
  const float* src = bev + (size_t)(b * 64) * 16384 + y * 128;
#pragma unroll
  for (int k = 0; k < 8; ++k) {
    int chunk = k * 256 + t;
    int ic = chunk >> 5, xq = chunk & 31;
    float4 v = *(const float4*)(src + ic * 16384 + xq * 4);
    int slot = xq ^ (ic >> 3);
    *(float4*)&lds[(ic * 32 + slot) * 4] = v;
  }
  __syncthreads();
  unsigned short* dst = nhwc + (size_t)blockIdx.x * 8192;
#pragma unroll
  for (int k = 0; k < 4; ++k) {
    int co = k * 256 + t;
    int x = co >> 3, icg = co & 7;
    int slot = (x >> 2) ^ icg;
    int w = x & 3;
    uint4 u;
    unsigned int* up = (unsigned int*)&u;
#pragma unroll
    for (int jj = 0; jj < 4; ++jj) {
      float v0 = lds[((icg * 8 + 2 * jj) * 32 + slot) * 4 + w];
      float v1 = lds[((icg * 8 + 2 * jj + 1) * 32 + slot) * 4 + w];
      up[jj] = (unsigned int)f2bf(v0) | ((unsigned int)f2bf(v1) << 16);
    }
    *(uint4*)(dst + x * 64 + icg * 8) = u;
  }
}

// ---------------------------------------------------------------------------
// K1b: pack weights (unchanged layouts)
//   wconv[o][gg8][oc256][j8] = conv_w[oc][gg*8+j][o/3][o%3]
//   wout [cg32][d256][j8]    = out_w[d][cg*8+j]
// ---------------------------------------------------------------------------
__global__ __launch_bounds__(256) void k1b_pack(const float* __restrict__ conv_w,
                                                const float* __restrict__ out_w,
                                                unsigned short* __restrict__ wconv,
                                                unsigned short* __restrict__ wout,
                                                float* __restrict__ zp) {
  const int tid = blockIdx.x * 256 + threadIdx.x;
  for (int idx = tid; idx < 9 * 8 * 256 * 8; idx += 16384) {
    int j = idx & 7, oc = (idx >> 3) & 255, g = (idx >> 11) & 7, o = idx >> 14;
    wconv[idx] = f2bf(conv_w[(oc * 64 + g * 8 + j) * 9 + o]);
  }
  for (int idx = tid; idx < 32 * 256 * 8; idx += 16384) {
    int j = idx & 7, d = (idx >> 3) & 255, g = idx >> 11;
    wout[idx] = f2bf(out_w[d * 256 + g * 8 + j]);
  }
  if (tid < 64) zp[tid] = 0.0f;
}

// ---------------------------------------------------------------------------
// K2 v5: 3x3 conv + bias + relu, implicit GEMM, D[oc][pix] = W[oc][k]·In[k][pix]
// 8-phase port of the m201 template (T3+T4+T5 + frag caching):
// block = (b,row-pair): 256 pix x 256 oc, 512 thr = 8 waves (2oc x 4pix),
// wave tile 128oc x 64pix, acc[8][4] = 128 VGPR.
// K = 9 tiles of 64 (tile o = one (dy,dx), 64 ic). Weights 32KB/tile,
// double-buffered (2x32KB); input 4-row halo (66,560B) staged once.
// Per tile, 4 quadrant phases of 16 MFMA:
//   ph0: read A-half0(8) + B-half0(4); waves 0-3 stage 4KB of tile o+1
//        -> barrier -> MFMA(h0,j0) -> barrier
//   ph1: read B-half1(4); waves 4-7 stage -> barrier -> MFMA(h0,j1) -> barrier
//   ph2: read A-half1(8)            -> barrier -> MFMA(h1,j0) -> barrier
//   ph3: vmcnt(0) (loads >=2 phases old) -> barrier -> MFMA(h1,j1) -> barrier
// 24 ds_read_b128/wave/tile (frag caching) => LDS pipe ~1.5k cyc < MFMA 2.5k.
// ---------------------------------------------------------------------------
#define K2_WOFF 66560

#define K2_READA(o, h) do {                                                   \
    const short8* wb_ = (const short8*)(smem + K2_WOFF + ((o)&1) * 32768);    \
    _Pragma("unroll")                                                         \
    for (int ic_ = 0; ic_ < 2; ++ic_)                                         \
      _Pragma("unroll")                                                       \
      for (int i_ = 0; i_ < 4; ++i_)                                          \
        aH[ic_*4+i_] = wb_[(ic_*4+g)*256 + wo*128 + (h)*64 + i_*16 + l15];    \
  } while (0)

#define K2_READB(dyr, dx, j, B) do {                                          \
    _Pragma("unroll")                                                         \
    for (int ic_ = 0; ic_ < 2; ++ic_)                                         \
      _Pragma("unroll")                                                       \
      for (int p_ = 0; p_ < 2; ++p_)                                          \
        B[ic_*2+p_] = lin[((rh+(dyr))*8 + ic_*4 + g)*130 + 1 + (dx) + xb +    \
                          l15 + ((j)*2 + p_)*16];                             \
  } while (0)

#define K2_STAGEW(o1, cbase) do {                                             \
    const unsigned short* ws_ = wconv + (size_t)(o1) * 16384;                 \
    char* wd_ = smem + K2_WOFF + ((o1)&1) * 32768;                            \
    _Pragma("unroll")                                                         \
    for (int c_ = 0; c_ < 4; ++c_)                                            \
      gload_lds16(ws_ + ((cbase)+c_) * 512 + lane * 8,                        \
                  wd_ + ((cbase)+c_) * 1024);                                 \
  } while (0)

#define K2_MF(h, j, B) do {                                                   \
    __builtin_amdgcn_s_setprio(1);                                            \
    _Pragma("unroll")                                                         \
    for (int i_ = 0; i_ < 4; ++i_)                                            \
      _Pragma("unroll")                                                       \
      for (int p_ = 0; p_ < 2; ++p_)                                          \
        _Pragma("unroll")                                                     \
        for (int ic_ = 0; ic_ < 2; ++ic_)                                     \
          acc[(h)*4+i_][(j)*2+p_] = __builtin_amdgcn_mfma_f32_16x16x32_bf16(  \
              aH[ic_*4+i_], B[ic_*2+p_], acc[(h)*4+i_][(j)*2+p_], 0, 0, 0);   \
    __builtin_amdgcn_s_setprio(0);                                            \
  } while (0)

__global__ __launch_bounds__(512, 2) void k2_conv(const unsigned short* __restrict__ nhwc,
                                                  const unsigned short* __restrict__ wconv,
                                                  const float* __restrict__ conv_b,
                                                  const float* __restrict__ zp,
                                                  unsigned short* __restrict__ value) {
  __shared__ __align__(16) char smem[132096];   // 66560 input + 2*32768 weights
  const short8* lin = (const short8*)smem;
  const int bid = blockIdx.x;
  const int swz = (bid & 7) * 128 + (bid >> 3);    // XCD swizzle: 2 images/XCD
  const int b = swz >> 6, yp = swz & 63;
  const int y0 = yp * 2;
  const int t = threadIdx.x, wid = t >> 6, lane = t & 63;
  const int wo = wid >> 2, wp = wid & 3;           // oc-half, pix-quarter
  const int g = lane >> 4, l15 = lane & 15;
  const int rh = wp >> 1;                          // row within pair
  const int xb = (wp & 1) * 64;                    // wave's pixel column base

  // ---- prologue: stage input rows y0-1..y0+2 (4160 chunks = 65 issues) ----
  const unsigned short* bevb = nhwc + (size_t)b * (128 * 128 * 64);
  for (int i = wid; i < 65; i += 8) {
    const int chunk = i * 64 + lane;
    const int ridx = chunk / 1040;
    const int rem = chunk - ridx * 1040;
    const int icg = rem / 130;
    const int c = rem - icg * 130;
    const int yy = y0 - 1 + ridx, xx = c - 1;
    const void* src = (yy >= 0 && yy < 128 && xx >= 0 && xx < 128)
                          ? (const void*)(bevb + ((yy * 128 + xx) * 64 + icg * 8))
                          : (const void*)zp;
    gload_lds16(src, smem + i * 1024);
  }
  // stage weight tile 0 into slot 0 (32 chunks: 4 per wave)
  K2_STAGEW(0, wid * 4);
  asm volatile("s_waitcnt vmcnt(0)" ::: "memory");
  __builtin_amdgcn_s_barrier();

  const f32x4 z4 = {0.f, 0.f, 0.f, 0.f};
  f32x4 acc[8][4];
#pragma unroll
  for (int i = 0; i < 8; ++i)
#pragma unroll
    for (int j = 0; j < 4; ++j) acc[i][j] = z4;

  short8 aH[8], b0[4], b1[4];

#pragma unroll
  for (int o = 0; o < 9; ++o) {
    const int dyr = o / 3, dx = o % 3 - 1;
    // ---- phase 0: A-half0 + B-half0 reads; waves 0-3 stage tile o+1 ----
    K2_READA(o, 0);
    K2_READB(dyr, dx, 0, b0);
    if (o < 8 && wid < 4) K2_STAGEW(o + 1, wid * 4);
    __builtin_amdgcn_s_barrier();
    K2_MF(0, 0, b0);
    __builtin_amdgcn_s_barrier();
    // ---- phase 1: B-half1 reads; waves 4-7 stage tile o+1 ----
    K2_READB(dyr, dx, 1, b1);
    if (o < 8 && wid >= 4) K2_STAGEW(o + 1, 16 + (wid - 4) * 4);
    __builtin_amdgcn_s_barrier();
    K2_MF(0, 1, b1);
    __builtin_amdgcn_s_barrier();
    // ---- phase 2: A-half1 reads ----
    K2_READA(o, 1);
    __builtin_amdgcn_s_barrier();
    K2_MF(1, 0, b0);
    __builtin_amdgcn_s_barrier();
    // ---- phase 3: no reads; publish next weight slot ----
    asm volatile("s_waitcnt vmcnt(0)" ::: "memory");
    __builtin_amdgcn_s_barrier();
    K2_MF(1, 1, b1);
    __builtin_amdgcn_s_barrier();
  }

  // ---- epilogue: bias + relu -> direct ushort4 stores (4 consecutive oc) ----
  const int y = y0 + rh;
  unsigned short* vrow = value + (((size_t)(b * 128 + y) * 128 + xb + l15) * 256);
#pragma unroll
  for (int ocf = 0; ocf < 8; ++ocf) {
    const int ocb = wo * 128 + ocf * 16 + g * 4;
    const float4 cb4 = *(const float4*)(conv_b + ocb);
#pragma unroll
    for (int pf = 0; pf < 4; ++pf) {
      ushort4 ov;
      float v0 = acc[ocf][pf][0] + cb4.x; ov.x = f2bf(v0 > 0.f ? v0 : 0.f);
      float v1 = acc[ocf][pf][1] + cb4.y; ov.y = f2bf(v1 > 0.f ? v1 : 0.f);
      float v2 = acc[ocf][pf][2] + cb4.z; ov.z = f2bf(v2 > 0.f ? v2 : 0.f);
      float v3 = acc[ocf][pf][3] + cb4.w; ov.w = f2bf(v3 > 0.f ? v3 : 0.f);
      *(ushort4*)(vrow + (size_t)pf * 16 * 256 + ocb) = ov;
    }
  }
}

// ---------------------------------------------------------------------------
// K3: per-query softmax + bilinear grid-sample + P-weighted sum (unchanged)
// ---------------------------------------------------------------------------
__global__ __launch_bounds__(256) void k3_sample(const float* __restrict__ queries,
                                                 const float* __restrict__ traj,
                                                 const float* __restrict__ attn_w,
                                                 const float* __restrict__ attn_b,
                                                 const unsigned short* __restrict__ value,
                                                 unsigned short* __restrict__ S) {
  const int wid = threadIdx.x >> 6, lane = threadIdx.x & 63;
  const int qg = blockIdx.x * 4 + wid;
  const int b = qg >> 10;
  const float4 qv = ((const float4*)queries)[qg * 64 + lane];
  float a[8];
#pragma unroll
  for (int p = 0; p < 8; ++p) {
    float4 wv = ((const float4*)attn_w)[p * 64 + lane];
    float d = qv.x * wv.x + qv.y * wv.y + qv.z * wv.z + qv.w * wv.w;
#pragma unroll
    for (int off = 32; off >= 1; off >>= 1) d += __shfl_xor(d, off);
    a[p] = d + attn_b[p];
  }
  float mx = a[0];
#pragma unroll
  for (int p = 1; p < 8; ++p) mx = fmaxf(mx, a[p]);
  float ssum = 0.f;
#pragma unroll
  for (int p = 0; p < 8; ++p) { a[p] = __expf(a[p] - mx); ssum += a[p]; }
  const float inv = 1.f / ssum;

  float acc0 = 0.f, acc1 = 0.f, acc2 = 0.f, acc3 = 0.f;
  const unsigned short* vb = value + (size_t)b * (128 * 128 * 256);
  const int coff = lane * 4;
#pragma unroll
  for (int p = 0; p < 8; ++p) {
    const float ty = traj[(qg * 8 + p) * 2 + 0];
    const float tx = traj[(qg * 8 + p) * 2 + 1];
    const float fx = (tx * 0.03125f + 1.f) * 64.f - 0.5f;
    const float fy = (ty * 0.03125f + 1.f) * 64.f - 0.5f;
    const float fx0 = floorf(fx), fy0 = floorf(fy);
    const int ix0 = (int)fx0, iy0 = (int)fy0;
    const float wx1 = fx - fx0, wx0 = 1.f - wx1;
    const float wy1 = fy - fy0, wy0 = 1.f - wy1;
    const float ap = a[p] * inv;
    const float cw[4] = {wx0 * wy0 * ap, wx1 * wy0 * ap, wx0 * wy1 * ap, wx1 * wy1 * ap};
    const int cx[4] = {ix0, ix0 + 1, ix0, ix0 + 1};
    const int cy[4] = {iy0, iy0, iy0 + 1, iy0 + 1};
#pragma unroll
    for (int cc = 0; cc < 4; ++cc) {
      if (cx[cc] >= 0 && cx[cc] < 128 && cy[cc] >= 0 && cy[cc] < 128) {
        const ushort4 v = *(const ushort4*)(vb + (cy[cc] * 128 + cx[cc]) * 256 + coff);
        acc0 += cw[cc] * bf2f(v.x);
        acc1 += cw[cc] * bf2f(v.y);
        acc2 += cw[cc] * bf2f(v.z);
        acc3 += cw[cc] * bf2f(v.w);
      }
    }
  }
  ushort4 o;
  o.x = f2bf(acc0); o.y = f2bf(acc1); o.z = f2bf(acc2); o.w = f2bf(acc3);
  *(ushort4*)(S + (size_t)qg * 256 + coff) = o;
}

// ---------------------------------------------------------------------------
// K4 v2: out[q][d] = S[q][:] . out_w[d][:] + out_b[d] + queries[q][d]
// (unchanged)
// ---------------------------------------------------------------------------
__global__ __launch_bounds__(256, 2) void k4_proj(const unsigned short* __restrict__ S,
                                                  const unsigned short* __restrict__ wout,
                                                  const float* __restrict__ out_b,
                                                  const float* __restrict__ queries,
                                                  float* __restrict__ out) {
  __shared__ __align__(16) char smem[16384];     // 2 x 512 chunks [gg4][q128]
  const short8* lds8 = (const short8*)smem;
  const short8* wp8 = (const short8*)wout;
  const int t = threadIdx.x, wid = t >> 6, lane = t & 63;
  const int wo = wid >> 1, wq = wid & 1;         // d-half, q-half
  const int q0 = blockIdx.x * 128;
  const int g = lane >> 4, l15 = lane & 15;
  const f32x4 z4 = {0.f, 0.f, 0.f, 0.f};
  f32x4 acc[8][4];
#pragma unroll
  for (int i = 0; i < 8; ++i)
#pragma unroll
    for (int j = 0; j < 4; ++j) acc[i][j] = z4;

  // stage ks=0
#pragma unroll
  for (int ii = 0; ii < 2; ++ii) {
    const int chunk = wid * 128 + ii * 64 + lane;
    const int gg = chunk >> 7, q = chunk & 127;
    gload_lds16(S + ((size_t)(q0 + q) * 256 + gg * 8), smem + wid * 2048 + ii * 1024);
  }
  __syncthreads();

#pragma unroll
  for (int ks = 0; ks < 8; ++ks) {
    if (ks < 7) {
      const int k1 = ks + 1;
#pragma unroll
      for (int ii = 0; ii < 2; ++ii) {
        const int chunk = wid * 128 + ii * 64 + lane;
        const int gg = chunk >> 7, q = chunk & 127;
        gload_lds16(S + ((size_t)(q0 + q) * 256 + k1 * 32 + gg * 8),
                    smem + ((k1 & 1) ? 8192 : 0) + wid * 2048 + ii * 1024);
      }
    }
    short8 af[8];
#pragma unroll
    for (int df = 0; df < 8; ++df)
      af[df] = wp8[(ks * 4 + g) * 256 + wo * 128 + df * 16 + l15];
    short8 bf[4];
    const short8* sb = lds8 + ((ks & 1) ? 512 : 0);
#pragma unroll
    for (int qf = 0; qf < 4; ++qf) bf[qf] = sb[g * 128 + wq * 64 + qf * 16 + l15];
    __builtin_amdgcn_s_setprio(1);
#pragma unroll
    for (int df = 0; df < 8; ++df)
#pragma unroll
      for (int qf = 0; qf < 4; ++qf)
        acc[df][qf] = __builtin_amdgcn_mfma_f32_16x16x32_bf16(af[df], bf[qf], acc[df][qf], 0, 0, 0);
    __builtin_amdgcn_s_setprio(0);
    __syncthreads();
  }

#pragma unroll
  for (int df = 0; df < 8; ++df) {
    const int db = wo * 128 + df * 16 + g * 4;
    const float4 ob4 = *(const float4*)(out_b + db);
#pragma unroll
    for (int qf = 0; qf < 4; ++qf) {
      const int q = q0 + wq * 64 + qf * 16 + l15;
      const float4 qv = *(const float4*)(queries + (size_t)q * 256 + db);
      float4 ov;
      ov.x = acc[df][qf][0] + ob4.x + qv.x;
      ov.y = acc[df][qf][1] + ob4.y + qv.y;
      ov.z = acc[df][qf][2] + ob4.z + qv.z;
      ov.w = acc[df][qf][3] + ob4.w + qv.w;
      *(float4*)(out + (size_t)q * 256 + db) = ov;
    }
  }
}

// ---------------------------------------------------------------------------
extern "C" void kernel_launch(void* const* d_in, const int* in_sizes, int n_in,
                              void* d_out, int out_size, void* d_ws, size_t ws_size,
                              hipStream_t stream) {
  const float* queries = (const float*)d_in[0];
  const float* traj    = (const float*)d_in[1];
  const float* bev     = (const float*)d_in[2];
  const float* attn_w  = (const float*)d_in[4];
  const float* attn_b  = (const float*)d_in[5];
  const float* conv_w  = (const float*)d_in[6];
  const float* conv_b  = (const float*)d_in[7];
  const float* out_w   = (const float*)d_in[8];
  const float* out_b   = (const float*)d_in[9];
  float* out = (float*)d_out;

  char* ws = (char*)d_ws;
  unsigned short* bev_nhwc = (unsigned short*)(ws);               //  33,554,432 B
  unsigned short* value    = (unsigned short*)(ws + 33554432);    // 134,217,728 B
  unsigned short* wconv    = (unsigned short*)(ws + 167772160);   //     294,912 B
  unsigned short* wout     = (unsigned short*)(ws + 168067072);   //     131,072 B
  unsigned short* Sbuf     = (unsigned short*)(ws + 168198144);   //   8,388,608 B
  float*          zp       = (float*)(ws + 176586752);            //         256 B

  k1_transpose<<<2048, 256, 0, stream>>>(bev, bev_nhwc);
  k1b_pack<<<64, 256, 0, stream>>>(conv_w, out_w, wconv, wout, zp);
  k2_conv<<<1024, 512, 0, stream>>>(bev_nhwc, wconv, conv_b, zp, value);
  k3_sample<<<4096, 256, 0, stream>>>(queries, traj, attn_w, attn_b, value, Sbuf);
  k4_proj<<<128, 256, 0, stream>>>(Sbuf, wout, out_b, queries, out);
}

// Round 6
// 166.660 us; speedup vs baseline: 1.1047x; 1.0938x over previous
//
#include <hip/hip_runtime.h>
#include <stdint.h>

// Problem constants: bs=16, Q=1024, P=8, D=256, Cin=64, H=W=128, Cout=256.

typedef __attribute__((ext_vector_type(8))) short short8;   // 8 bf16 (4 VGPR)
typedef __attribute__((ext_vector_type(4))) float f32x4;    // MFMA acc

__device__ __forceinline__ unsigned short f2bf(float f) {
  union { float f; unsigned int u; } v; v.f = f;
  unsigned int r = (v.u + 0x7FFFu + ((v.u >> 16) & 1u)) >> 16;  // RNE
  return (unsigned short)r;
}
__device__ __forceinline__ float bf2f(unsigned short h) {
  union { unsigned int u; float f; } v; v.u = ((unsigned int)h) << 16;
  return v.f;
}

// async global->LDS, 16B per lane; LDS dest wave-uniform (HW adds lane*16),
// global src per-lane.
__device__ __forceinline__ void gload_lds16(const void* g, void* l) {
  __builtin_amdgcn_global_load_lds(
      (const __attribute__((address_space(1))) unsigned int*)g,
      (__attribute__((address_space(3))) unsigned int*)l, 16, 0, 0);
}

// ---------------------------------------------------------------------------
// K1: bev (16,64,128,128) f32 NCHW -> bev_nhwc (16,128,128,64) bf16 (unchanged)
// ---------------------------------------------------------------------------
__global__ __launch_bounds__(256) void k1_transpose(const float* __restrict__ bev,
                                                    unsigned short* __restrict__ nhwc) {
  __shared__ __align__(16) float lds[64 * 32 * 4];
  const int b = blockIdx.x >> 7, y = blockIdx.x & 127;
  const int t = threadIdx.x;
  const float* src = bev + (size_t)(b * 64) * 16384 + y * 128;
#pragma unroll
  for (int k = 0; k < 8; ++k) {
    int chunk = k * 256 + t;
    int ic = chunk >> 5, xq = chunk & 31;
    float4 v = *(const float4*)(src + ic * 16384 + xq * 4);
    int slot = xq ^ (ic >> 3);
    *(float4*)&lds[(ic * 32 + slot) * 4] = v;
  }
  __syncthreads();
  unsigned short* dst = nhwc + (size_t)blockIdx.x * 8192;
#pragma unroll
  for (int k = 0; k < 4; ++k) {
    int co = k * 256 + t;
    int x = co >> 3, icg = co & 7;
    int slot = (x >> 2) ^ icg;
    int w = x & 3;
    uint4 u;
    unsigned int* up = (unsigned int*)&u;
#pragma unroll
    for (int jj = 0; jj < 4; ++jj) {
      float v0 = lds[((icg * 8 + 2 * jj) * 32 + slot) * 4 + w];
      float v1 = lds[((icg * 8 + 2 * jj + 1) * 32 + slot) * 4 + w];
      up[jj] = (unsigned int)f2bf(v0) | ((unsigned int)f2bf(v1) << 16);
    }
    *(uint4*)(dst + x * 64 + icg * 8) = u;
  }
}

// ---------------------------------------------------------------------------
// K1b: pack weights (unchanged layouts)
//   wconv[o][gg8][oc256][j8] = conv_w[oc][gg*8+j][o/3][o%3]
//   wout [cg32][d256][j8]    = out_w[d][cg*8+j]
// ---------------------------------------------------------------------------
__global__ __launch_bounds__(256) void k1b_pack(const float* __restrict__ conv_w,
                                                const float* __restrict__ out_w,
                                                unsigned short* __restrict__ wconv,
                                                unsigned short* __restrict__ wout,
                                                float* __restrict__ zp) {
  const int tid = blockIdx.x * 256 + threadIdx.x;
  for (int idx = tid; idx < 9 * 8 * 256 * 8; idx += 16384) {
    int j = idx & 7, oc = (idx >> 3) & 255, g = (idx >> 11) & 7, o = idx >> 14;
    wconv[idx] = f2bf(conv_w[(oc * 64 + g * 8 + j) * 9 + o]);
  }
  for (int idx = tid; idx < 32 * 256 * 8; idx += 16384) {
    int j = idx & 7, d = (idx >> 3) & 255, g = idx >> 11;
    wout[idx] = f2bf(out_w[d * 256 + g * 8 + j]);
  }
  if (tid < 64) zp[tid] = 0.0f;
}

// ---------------------------------------------------------------------------
// K2 v6: 3x3 conv + bias + relu, implicit GEMM, D[oc][pix] = W[oc][k]·In[k][pix]
// BARRIER-FREE K-loop. block = (b,row-pair): 256 pix x 256 oc, 512 thr =
// 8 waves (2oc x 4pix), wave tile 128oc x 64pix, acc[8][4] = 128 VGPR.
// Input 4-row halo staged once in LDS (66,560B) -> READ-ONLY for whole loop;
// single __syncthreads after prologue. Weights are NOT staged in LDS: each
// wave reads its A-frags directly from L2-resident wconv (288KB, broadcast)
// into registers, double-buffered at K=32 granularity (prefetch distance 1
// step ~310cyc > L2 latency). B-frags from LDS, also double-buffered.
// No s_barrier / no waitcnt asm in the loop: compiler emits counted
// vmcnt/lgkmcnt per register dependency; waves free-run (no skew cost).
// Per step s (K=32, s=0..17, o=s>>1, ich=s&1):
//   READB(s+1) -> bb[(s+1)&1] ; MFMA(A[s&1], bb[s&1]) ; LOADA(s+2) -> A[s&1]
// ---------------------------------------------------------------------------
#define K2_LOADA(s, A) do {                                                   \
    _Pragma("unroll")                                                         \
    for (int ocf_ = 0; ocf_ < 8; ++ocf_)                                      \
      A[ocf_] = gA[(4 * (s) + g) * 256 + wo * 128 + ocf_ * 16 + l15];         \
  } while (0)

#define K2_READB(s, B) do {                                                   \
    const int o_ = (s) >> 1, ich_ = (s) & 1;                                  \
    const int dyr_ = o_ / 3, dx_ = o_ - dyr_ * 3 - 1;                         \
    _Pragma("unroll")                                                         \
    for (int pf_ = 0; pf_ < 4; ++pf_)                                         \
      B[pf_] = lin[((rh + dyr_) * 8 + ich_ * 4 + g) * 130 + 1 + dx_ + xb +    \
                   l15 + pf_ * 16];                                           \
  } while (0)

#define K2_MFMA(A, B) do {                                                    \
    __builtin_amdgcn_s_setprio(1);                                            \
    _Pragma("unroll")                                                         \
    for (int ocf_ = 0; ocf_ < 8; ++ocf_)                                      \
      _Pragma("unroll")                                                       \
      for (int pf_ = 0; pf_ < 4; ++pf_)                                       \
        acc[ocf_][pf_] = __builtin_amdgcn_mfma_f32_16x16x32_bf16(             \
            A[ocf_], B[pf_], acc[ocf_][pf_], 0, 0, 0);                        \
    __builtin_amdgcn_s_setprio(0);                                            \
  } while (0)

__global__ __launch_bounds__(512, 2) void k2_conv(const unsigned short* __restrict__ nhwc,
                                                  const unsigned short* __restrict__ wconv,
                                                  const float* __restrict__ conv_b,
                                                  const float* __restrict__ zp,
                                                  unsigned short* __restrict__ value) {
  __shared__ __align__(16) char smem[66560];     // input halo only
  const short8* lin = (const short8*)smem;
  const short8* gA = (const short8*)wconv;
  const int bid = blockIdx.x;
  const int swz = (bid & 7) * 128 + (bid >> 3);    // XCD swizzle: 2 images/XCD
  const int b = swz >> 6, yp = swz & 63;
  const int y0 = yp * 2;
  const int t = threadIdx.x, wid = t >> 6, lane = t & 63;
  const int wo = wid >> 2, wp = wid & 3;           // oc-half, pix-quarter
  const int g = lane >> 4, l15 = lane & 15;
  const int rh = wp >> 1;                          // row within pair
  const int xb = (wp & 1) * 64;                    // wave's pixel column base

  // ---- prologue: stage input rows y0-1..y0+2 (4160 chunks = 65 issues) ----
  const unsigned short* bevb = nhwc + (size_t)b * (128 * 128 * 64);
  for (int i = wid; i < 65; i += 8) {
    const int chunk = i * 64 + lane;
    const int ridx = chunk / 1040;
    const int rem = chunk - ridx * 1040;
    const int icg = rem / 130;
    const int c = rem - icg * 130;
    const int yy = y0 - 1 + ridx, xx = c - 1;
    const void* src = (yy >= 0 && yy < 128 && xx >= 0 && xx < 128)
                          ? (const void*)(bevb + ((yy * 128 + xx) * 64 + icg * 8))
                          : (const void*)zp;
    gload_lds16(src, smem + i * 1024);
  }
  __syncthreads();   // drains gload_lds (vmcnt0) + barrier; LDS read-only after

  const f32x4 z4 = {0.f, 0.f, 0.f, 0.f};
  f32x4 acc[8][4];
#pragma unroll
  for (int i = 0; i < 8; ++i)
#pragma unroll
    for (int j = 0; j < 4; ++j) acc[i][j] = z4;

  short8 A[2][8], bb[2][4];
  K2_LOADA(0, A[0]);
  K2_LOADA(1, A[1]);
  K2_READB(0, bb[0]);

#pragma unroll
  for (int s = 0; s < 18; ++s) {
    if (s < 17) K2_READB(s + 1, bb[(s + 1) & 1]);   // LDS prefetch next step
    K2_MFMA(A[s & 1], bb[s & 1]);                   // compute current step
    if (s + 2 < 18) K2_LOADA(s + 2, A[s & 1]);      // global prefetch dist-1
  }

  // ---- epilogue: bias + relu -> direct ushort4 stores (4 consecutive oc) ----
  const int y = y0 + rh;
  unsigned short* vrow = value + (((size_t)(b * 128 + y) * 128 + xb + l15) * 256);
#pragma unroll
  for (int ocf = 0; ocf < 8; ++ocf) {
    const int ocb = wo * 128 + ocf * 16 + g * 4;
    const float4 cb4 = *(const float4*)(conv_b + ocb);
#pragma unroll
    for (int pf = 0; pf < 4; ++pf) {
      ushort4 ov;
      float v0 = acc[ocf][pf][0] + cb4.x; ov.x = f2bf(v0 > 0.f ? v0 : 0.f);
      float v1 = acc[ocf][pf][1] + cb4.y; ov.y = f2bf(v1 > 0.f ? v1 : 0.f);
      float v2 = acc[ocf][pf][2] + cb4.z; ov.z = f2bf(v2 > 0.f ? v2 : 0.f);
      float v3 = acc[ocf][pf][3] + cb4.w; ov.w = f2bf(v3 > 0.f ? v3 : 0.f);
      *(ushort4*)(vrow + (size_t)pf * 16 * 256 + ocb) = ov;
    }
  }
}

// ---------------------------------------------------------------------------
// K3: per-query softmax + bilinear grid-sample + P-weighted sum (unchanged)
// ---------------------------------------------------------------------------
__global__ __launch_bounds__(256) void k3_sample(const float* __restrict__ queries,
                                                 const float* __restrict__ traj,
                                                 const float* __restrict__ attn_w,
                                                 const float* __restrict__ attn_b,
                                                 const unsigned short* __restrict__ value,
                                                 unsigned short* __restrict__ S) {
  const int wid = threadIdx.x >> 6, lane = threadIdx.x & 63;
  const int qg = blockIdx.x * 4 + wid;
  const int b = qg >> 10;
  const float4 qv = ((const float4*)queries)[qg * 64 + lane];
  float a[8];
#pragma unroll
  for (int p = 0; p < 8; ++p) {
    float4 wv = ((const float4*)attn_w)[p * 64 + lane];
    float d = qv.x * wv.x + qv.y * wv.y + qv.z * wv.z + qv.w * wv.w;
#pragma unroll
    for (int off = 32; off >= 1; off >>= 1) d += __shfl_xor(d, off);
    a[p] = d + attn_b[p];
  }
  float mx = a[0];
#pragma unroll
  for (int p = 1; p < 8; ++p) mx = fmaxf(mx, a[p]);
  float ssum = 0.f;
#pragma unroll
  for (int p = 0; p < 8; ++p) { a[p] = __expf(a[p] - mx); ssum += a[p]; }
  const float inv = 1.f / ssum;

  float acc0 = 0.f, acc1 = 0.f, acc2 = 0.f, acc3 = 0.f;
  const unsigned short* vb = value + (size_t)b * (128 * 128 * 256);
  const int coff = lane * 4;
#pragma unroll
  for (int p = 0; p < 8; ++p) {
    const float ty = traj[(qg * 8 + p) * 2 + 0];
    const float tx = traj[(qg * 8 + p) * 2 + 1];
    const float fx = (tx * 0.03125f + 1.f) * 64.f - 0.5f;
    const float fy = (ty * 0.03125f + 1.f) * 64.f - 0.5f;
    const float fx0 = floorf(fx), fy0 = floorf(fy);
    const int ix0 = (int)fx0, iy0 = (int)fy0;
    const float wx1 = fx - fx0, wx0 = 1.f - wx1;
    const float wy1 = fy - fy0, wy0 = 1.f - wy1;
    const float ap = a[p] * inv;
    const float cw[4] = {wx0 * wy0 * ap, wx1 * wy0 * ap, wx0 * wy1 * ap, wx1 * wy1 * ap};
    const int cx[4] = {ix0, ix0 + 1, ix0, ix0 + 1};
    const int cy[4] = {iy0, iy0, iy0 + 1, iy0 + 1};
#pragma unroll
    for (int cc = 0; cc < 4; ++cc) {
      if (cx[cc] >= 0 && cx[cc] < 128 && cy[cc] >= 0 && cy[cc] < 128) {
        const ushort4 v = *(const ushort4*)(vb + (cy[cc] * 128 + cx[cc]) * 256 + coff);
        acc0 += cw[cc] * bf2f(v.x);
        acc1 += cw[cc] * bf2f(v.y);
        acc2 += cw[cc] * bf2f(v.z);
        acc3 += cw[cc] * bf2f(v.w);
      }
    }
  }
  ushort4 o;
  o.x = f2bf(acc0); o.y = f2bf(acc1); o.z = f2bf(acc2); o.w = f2bf(acc3);
  *(ushort4*)(S + (size_t)qg * 256 + coff) = o;
}

// ---------------------------------------------------------------------------
// K4 v2: out[q][d] = S[q][:] . out_w[d][:] + out_b[d] + queries[q][d]
// (unchanged)
// ---------------------------------------------------------------------------
__global__ __launch_bounds__(256, 2) void k4_proj(const unsigned short* __restrict__ S,
                                                  const unsigned short* __restrict__ wout,
                                                  const float* __restrict__ out_b,
                                                  const float* __restrict__ queries,
                                                  float* __restrict__ out) {
  __shared__ __align__(16) char smem[16384];     // 2 x 512 chunks [gg4][q128]
  const short8* lds8 = (const short8*)smem;
  const short8* wp8 = (const short8*)wout;
  const int t = threadIdx.x, wid = t >> 6, lane = t & 63;
  const int wo = wid >> 1, wq = wid & 1;         // d-half, q-half
  const int q0 = blockIdx.x * 128;
  const int g = lane >> 4, l15 = lane & 15;
  const f32x4 z4 = {0.f, 0.f, 0.f, 0.f};
  f32x4 acc[8][4];
#pragma unroll
  for (int i = 0; i < 8; ++i)
#pragma unroll
    for (int j = 0; j < 4; ++j) acc[i][j] = z4;

  // stage ks=0
#pragma unroll
  for (int ii = 0; ii < 2; ++ii) {
    const int chunk = wid * 128 + ii * 64 + lane;
    const int gg = chunk >> 7, q = chunk & 127;
    gload_lds16(S + ((size_t)(q0 + q) * 256 + gg * 8), smem + wid * 2048 + ii * 1024);
  }
  __syncthreads();

#pragma unroll
  for (int ks = 0; ks < 8; ++ks) {
    if (ks < 7) {
      const int k1 = ks + 1;
#pragma unroll
      for (int ii = 0; ii < 2; ++ii) {
        const int chunk = wid * 128 + ii * 64 + lane;
        const int gg = chunk >> 7, q = chunk & 127;
        gload_lds16(S + ((size_t)(q0 + q) * 256 + k1 * 32 + gg * 8),
                    smem + ((k1 & 1) ? 8192 : 0) + wid * 2048 + ii * 1024);
      }
    }
    short8 af[8];
#pragma unroll
    for (int df = 0; df < 8; ++df)
      af[df] = wp8[(ks * 4 + g) * 256 + wo * 128 + df * 16 + l15];
    short8 bf[4];
    const short8* sb = lds8 + ((ks & 1) ? 512 : 0);
#pragma unroll
    for (int qf = 0; qf < 4; ++qf) bf[qf] = sb[g * 128 + wq * 64 + qf * 16 + l15];
    __builtin_amdgcn_s_setprio(1);
#pragma unroll
    for (int df = 0; df < 8; ++df)
#pragma unroll
      for (int qf = 0; qf < 4; ++qf)
        acc[df][qf] = __builtin_amdgcn_mfma_f32_16x16x32_bf16(af[df], bf[qf], acc[df][qf], 0, 0, 0);
    __builtin_amdgcn_s_setprio(0);
    __syncthreads();
  }

#pragma unroll
  for (int df = 0; df < 8; ++df) {
    const int db = wo * 128 + df * 16 + g * 4;
    const float4 ob4 = *(const float4*)(out_b + db);
#pragma unroll
    for (int qf = 0; qf < 4; ++qf) {
      const int q = q0 + wq * 64 + qf * 16 + l15;
      const float4 qv = *(const float4*)(queries + (size_t)q * 256 + db);
      float4 ov;
      ov.x = acc[df][qf][0] + ob4.x + qv.x;
      ov.y = acc[df][qf][1] + ob4.y + qv.y;
      ov.z = acc[df][qf][2] + ob4.z + qv.z;
      ov.w = acc[df][qf][3] + ob4.w + qv.w;
      *(float4*)(out + (size_t)q * 256 + db) = ov;
    }
  }
}

// ---------------------------------------------------------------------------
extern "C" void kernel_launch(void* const* d_in, const int* in_sizes, int n_in,
                              void* d_out, int out_size, void* d_ws, size_t ws_size,
                              hipStream_t stream) {
  const float* queries = (const float*)d_in[0];
  const float* traj    = (const float*)d_in[1];
  const float* bev     = (const float*)d_in[2];
  const float* attn_w  = (const float*)d_in[4];
  const float* attn_b  = (const float*)d_in[5];
  const float* conv_w  = (const float*)d_in[6];
  const float* conv_b  = (const float*)d_in[7];
  const float* out_w   = (const float*)d_in[8];
  const float* out_b   = (const float*)d_in[9];
  float* out = (float*)d_out;

  char* ws = (char*)d_ws;
  unsigned short* bev_nhwc = (unsigned short*)(ws);               //  33,554,432 B
  unsigned short* value    = (unsigned short*)(ws + 33554432);    // 134,217,728 B
  unsigned short* wconv    = (unsigned short*)(ws + 167772160);   //     294,912 B
  unsigned short* wout     = (unsigned short*)(ws + 168067072);   //     131,072 B
  unsigned short* Sbuf     = (unsigned short*)(ws + 168198144);   //   8,388,608 B
  float*          zp       = (float*)(ws + 176586752);            //         256 B

  k1_transpose<<<2048, 256, 0, stream>>>(bev, bev_nhwc);
  k1b_pack<<<64, 256, 0, stream>>>(conv_w, out_w, wconv, wout, zp);
  k2_conv<<<1024, 512, 0, stream>>>(bev_nhwc, wconv, conv_b, zp, value);
  k3_sample<<<4096, 256, 0, stream>>>(queries, traj, attn_w, attn_b, value, Sbuf);
  k4_proj<<<128, 256, 0, stream>>>(Sbuf, wout, out_b, queries, out);
}

// Round 7
// 160.450 us; speedup vs baseline: 1.1475x; 1.0387x over previous
//
#include <hip/hip_runtime.h>
#include <stdint.h>

// Problem constants: bs=16, Q=1024, P=8, D=256, Cin=64, H=W=128, Cout=256.

typedef __attribute__((ext_vector_type(8))) short short8;   // 8 bf16 (4 VGPR)
typedef __attribute__((ext_vector_type(4))) float f32x4;    // MFMA acc

__device__ __forceinline__ unsigned short f2bf(float f) {
  union { float f; unsigned int u; } v; v.f = f;
  unsigned int r = (v.u + 0x7FFFu + ((v.u >> 16) & 1u)) >> 16;  // RNE
  return (unsigned short)r;
}
__device__ __forceinline__ float bf2f(unsigned short h) {
  union { unsigned int u; float f; } v; v.u = ((unsigned int)h) << 16;
  return v.f;
}

// async global->LDS, 16B per lane; LDS dest wave-uniform (HW adds lane*16),
// global src per-lane.
__device__ __forceinline__ void gload_lds16(const void* g, void* l) {
  __builtin_amdgcn_global_load_lds(
      (const __attribute__((address_space(1))) unsigned int*)g,
      (__attribute__((address_space(3))) unsigned int*)l, 16, 0, 0);
}

// ---------------------------------------------------------------------------
// K1: bev (16,64,128,128) f32 NCHW -> bev_nhwc (16,128,128,64) bf16 (unchanged)
// ---------------------------------------------------------------------------
__global__ __launch_bounds__(256) void k1_transpose(const float* __restrict__ bev,
                                                    unsigned short* __restrict__ nhwc) {
  __shared__ __align__(16) float lds[64 * 32 * 4];
  const int b = blockIdx.x >> 7, y = blockIdx.x & 127;
  const int t = threadIdx.x;
  const float* src = bev + (size_t)(b * 64) * 16384 + y * 128;
#pragma unroll
  for (int k = 0; k < 8; ++k) {
    int chunk = k * 256 + t;
    int ic = chunk >> 5, xq = chunk & 31;
    float4 v = *(const float4*)(src + ic * 16384 + xq * 4);
    int slot = xq ^ (ic >> 3);
    *(float4*)&lds[(ic * 32 + slot) * 4] = v;
  }
  __syncthreads();
  unsigned short* dst = nhwc + (size_t)blockIdx.x * 8192;
#pragma unroll
  for (int k = 0; k < 4; ++k) {
    int co = k * 256 + t;
    int x = co >> 3, icg = co & 7;
    int slot = (x >> 2) ^ icg;
    int w = x & 3;
    uint4 u;
    unsigned int* up = (unsigned int*)&u;
#pragma unroll
    for (int jj = 0; jj < 4; ++jj) {
      float v0 = lds[((icg * 8 + 2 * jj) * 32 + slot) * 4 + w];
      float v1 = lds[((icg * 8 + 2 * jj + 1) * 32 + slot) * 4 + w];
      up[jj] = (unsigned int)f2bf(v0) | ((unsigned int)f2bf(v1) << 16);
    }
    *(uint4*)(dst + x * 64 + icg * 8) = u;
  }
}

// ---------------------------------------------------------------------------
// K1b: pack weights (unchanged layouts)
//   wconv[o][gg8][oc256][j8] = conv_w[oc][gg*8+j][o/3][o%3]
//   wout [cg32][d256][j8]    = out_w[d][cg*8+j]
// ---------------------------------------------------------------------------
__global__ __launch_bounds__(256) void k1b_pack(const float* __restrict__ conv_w,
                                                const float* __restrict__ out_w,
                                                unsigned short* __restrict__ wconv,
                                                unsigned short* __restrict__ wout,
                                                float* __restrict__ zp) {
  const int tid = blockIdx.x * 256 + threadIdx.x;
  for (int idx = tid; idx < 9 * 8 * 256 * 8; idx += 16384) {
    int j = idx & 7, oc = (idx >> 3) & 255, g = (idx >> 11) & 7, o = idx >> 14;
    wconv[idx] = f2bf(conv_w[(oc * 64 + g * 8 + j) * 9 + o]);
  }
  for (int idx = tid; idx < 32 * 256 * 8; idx += 16384) {
    int j = idx & 7, d = (idx >> 3) & 255, g = idx >> 11;
    wout[idx] = f2bf(out_w[d * 256 + g * 8 + j]);
  }
  if (tid < 64) zp[tid] = 0.0f;
}

// ---------------------------------------------------------------------------
// K2 v7: 3x3 conv + bias + relu, implicit GEMM, D[oc][pix] = W[oc][k]·In[k][pix]
// Barrier-free K-loop (v6 structure) with rebalanced wave tile:
// 8 waves = 4 oc-groups x 2 rows; wave tile 64 oc x 128 pix (acc[4][8]).
// A (weights): 4 direct global loads/wave/step from L2-resident wconv,
//   double-buffered, prefetch distance 2 (issued after the MFMA burst,
//   WAR-clean). Redundancy 2x (was 4x) -> 32KB/step/block L1/L2 traffic.
// B (pixels): 8 ds_read_b128/wave/step from the read-only halo, single-
//   buffered in two halves (keeps total regs ~220 < 256 cliff).
// No barriers / no setprio / no waitcnt asm in the loop.
// ---------------------------------------------------------------------------
#define K2_LOADA(s, A) do {                                                   \
    _Pragma("unroll")                                                         \
    for (int ocf_ = 0; ocf_ < 4; ++ocf_)                                      \
      A[ocf_] = gA[(4 * (s) + g) * 256 + wo * 64 + ocf_ * 16 + l15];          \
  } while (0)

#define K2_READB(s, h, B) do {                                                \
    const int o_ = (s) >> 1, ich_ = (s) & 1;                                  \
    const int dyr_ = o_ / 3, dx_ = o_ - dyr_ * 3 - 1;                         \
    _Pragma("unroll")                                                         \
    for (int pf_ = 0; pf_ < 4; ++pf_)                                         \
      B[pf_] = lin[((rh + dyr_) * 8 + ich_ * 4 + g) * 130 + 1 + dx_ +         \
                   ((h) * 4 + pf_) * 16 + l15];                               \
  } while (0)

#define K2_MF(A, B, h) do {                                                   \
    _Pragma("unroll")                                                         \
    for (int ocf_ = 0; ocf_ < 4; ++ocf_)                                      \
      _Pragma("unroll")                                                       \
      for (int pf_ = 0; pf_ < 4; ++pf_)                                       \
        acc[ocf_][(h) * 4 + pf_] = __builtin_amdgcn_mfma_f32_16x16x32_bf16(   \
            A[ocf_], B[pf_], acc[ocf_][(h) * 4 + pf_], 0, 0, 0);              \
  } while (0)

__global__ __launch_bounds__(512, 2) void k2_conv(const unsigned short* __restrict__ nhwc,
                                                  const unsigned short* __restrict__ wconv,
                                                  const float* __restrict__ conv_b,
                                                  const float* __restrict__ zp,
                                                  unsigned short* __restrict__ value) {
  __shared__ __align__(16) char smem[66560];     // input halo only
  const short8* lin = (const short8*)smem;
  const short8* gA = (const short8*)wconv;
  const int bid = blockIdx.x;
  const int swz = (bid & 7) * 128 + (bid >> 3);    // XCD swizzle: 2 images/XCD
  const int b = swz >> 6, yp = swz & 63;
  const int y0 = yp * 2;
  const int t = threadIdx.x, wid = t >> 6, lane = t & 63;
  const int wo = wid >> 1, rh = wid & 1;           // oc-quarter, row-in-pair
  const int g = lane >> 4, l15 = lane & 15;

  // ---- prologue: stage input rows y0-1..y0+2 (4160 chunks = 65 issues) ----
  const unsigned short* bevb = nhwc + (size_t)b * (128 * 128 * 64);
  for (int i = wid; i < 65; i += 8) {
    const int chunk = i * 64 + lane;
    const int ridx = chunk / 1040;
    const int rem = chunk - ridx * 1040;
    const int icg = rem / 130;
    const int c = rem - icg * 130;
    const int yy = y0 - 1 + ridx, xx = c - 1;
    const void* src = (yy >= 0 && yy < 128 && xx >= 0 && xx < 128)
                          ? (const void*)(bevb + ((yy * 128 + xx) * 64 + icg * 8))
                          : (const void*)zp;
    gload_lds16(src, smem + i * 1024);
  }
  __syncthreads();   // drains gload_lds (vmcnt0) + barrier; LDS read-only after

  const f32x4 z4 = {0.f, 0.f, 0.f, 0.f};
  f32x4 acc[4][8];
#pragma unroll
  for (int i = 0; i < 4; ++i)
#pragma unroll
    for (int j = 0; j < 8; ++j) acc[i][j] = z4;

  short8 A0[4], A1[4], B0[4], B1[4];
  K2_LOADA(0, A0);
  K2_LOADA(1, A1);

#pragma unroll
  for (int s = 0; s < 18; ++s) {
    K2_READB(s, 0, B0);                             // LDS reads for this step
    K2_READB(s, 1, B1);
    if (s & 1) {
      K2_MF(A1, B0, 0);
      K2_MF(A1, B1, 1);
      if (s + 2 < 18) K2_LOADA(s + 2, A1);          // global prefetch dist-2
    } else {
      K2_MF(A0, B0, 0);
      K2_MF(A0, B1, 1);
      if (s + 2 < 18) K2_LOADA(s + 2, A0);
    }
  }

  // ---- epilogue: bias + relu -> direct ushort4 stores (4 consecutive oc) ----
  const int y = y0 + rh;
  unsigned short* vrow = value + (((size_t)(b * 128 + y) * 128 + l15) * 256);
#pragma unroll
  for (int ocf = 0; ocf < 4; ++ocf) {
    const int ocb = wo * 64 + ocf * 16 + g * 4;
    const float4 cb4 = *(const float4*)(conv_b + ocb);
#pragma unroll
    for (int pf = 0; pf < 8; ++pf) {
      ushort4 ov;
      float v0 = acc[ocf][pf][0] + cb4.x; ov.x = f2bf(v0 > 0.f ? v0 : 0.f);
      float v1 = acc[ocf][pf][1] + cb4.y; ov.y = f2bf(v1 > 0.f ? v1 : 0.f);
      float v2 = acc[ocf][pf][2] + cb4.z; ov.z = f2bf(v2 > 0.f ? v2 : 0.f);
      float v3 = acc[ocf][pf][3] + cb4.w; ov.w = f2bf(v3 > 0.f ? v3 : 0.f);
      *(ushort4*)(vrow + (size_t)pf * 16 * 256 + ocb) = ov;
    }
  }
}

// ---------------------------------------------------------------------------
// K3: per-query softmax + bilinear grid-sample + P-weighted sum (unchanged)
// ---------------------------------------------------------------------------
__global__ __launch_bounds__(256) void k3_sample(const float* __restrict__ queries,
                                                 const float* __restrict__ traj,
                                                 const float* __restrict__ attn_w,
                                                 const float* __restrict__ attn_b,
                                                 const unsigned short* __restrict__ value,
                                                 unsigned short* __restrict__ S) {
  const int wid = threadIdx.x >> 6, lane = threadIdx.x & 63;
  const int qg = blockIdx.x * 4 + wid;
  const int b = qg >> 10;
  const float4 qv = ((const float4*)queries)[qg * 64 + lane];
  float a[8];
#pragma unroll
  for (int p = 0; p < 8; ++p) {
    float4 wv = ((const float4*)attn_w)[p * 64 + lane];
    float d = qv.x * wv.x + qv.y * wv.y + qv.z * wv.z + qv.w * wv.w;
#pragma unroll
    for (int off = 32; off >= 1; off >>= 1) d += __shfl_xor(d, off);
    a[p] = d + attn_b[p];
  }
  float mx = a[0];
#pragma unroll
  for (int p = 1; p < 8; ++p) mx = fmaxf(mx, a[p]);
  float ssum = 0.f;
#pragma unroll
  for (int p = 0; p < 8; ++p) { a[p] = __expf(a[p] - mx); ssum += a[p]; }
  const float inv = 1.f / ssum;

  float acc0 = 0.f, acc1 = 0.f, acc2 = 0.f, acc3 = 0.f;
  const unsigned short* vb = value + (size_t)b * (128 * 128 * 256);
  const int coff = lane * 4;
#pragma unroll
  for (int p = 0; p < 8; ++p) {
    const float ty = traj[(qg * 8 + p) * 2 + 0];
    const float tx = traj[(qg * 8 + p) * 2 + 1];
    const float fx = (tx * 0.03125f + 1.f) * 64.f - 0.5f;
    const float fy = (ty * 0.03125f + 1.f) * 64.f - 0.5f;
    const float fx0 = floorf(fx), fy0 = floorf(fy);
    const int ix0 = (int)fx0, iy0 = (int)fy0;
    const float wx1 = fx - fx0, wx0 = 1.f - wx1;
    const float wy1 = fy - fy0, wy0 = 1.f - wy1;
    const float ap = a[p] * inv;
    const float cw[4] = {wx0 * wy0 * ap, wx1 * wy0 * ap, wx0 * wy1 * ap, wx1 * wy1 * ap};
    const int cx[4] = {ix0, ix0 + 1, ix0, ix0 + 1};
    const int cy[4] = {iy0, iy0, iy0 + 1, iy0 + 1};
#pragma unroll
    for (int cc = 0; cc < 4; ++cc) {
      if (cx[cc] >= 0 && cx[cc] < 128 && cy[cc] >= 0 && cy[cc] < 128) {
        const ushort4 v = *(const ushort4*)(vb + (cy[cc] * 128 + cx[cc]) * 256 + coff);
        acc0 += cw[cc] * bf2f(v.x);
        acc1 += cw[cc] * bf2f(v.y);
        acc2 += cw[cc] * bf2f(v.z);
        acc3 += cw[cc] * bf2f(v.w);
      }
    }
  }
  ushort4 o;
  o.x = f2bf(acc0); o.y = f2bf(acc1); o.z = f2bf(acc2); o.w = f2bf(acc3);
  *(ushort4*)(S + (size_t)qg * 256 + coff) = o;
}

// ---------------------------------------------------------------------------
// K4 v3: out[q][d] = S[q][:] . out_w[d][:] + out_b[d] + queries[q][d]
// 256 blocks of 64q x 256d (was 128 blocks -> half the CUs idle).
// 4 waves, each 64d x 64q, acc[4][4]; S staged dbuf 2x4KB; wout from L2.
// ---------------------------------------------------------------------------
__global__ __launch_bounds__(256, 2) void k4_proj(const unsigned short* __restrict__ S,
                                                  const unsigned short* __restrict__ wout,
                                                  const float* __restrict__ out_b,
                                                  const float* __restrict__ queries,
                                                  float* __restrict__ out) {
  __shared__ __align__(16) char smem[8192];      // 2 x 256 chunks [gg4][q64]
  const short8* lds8 = (const short8*)smem;
  const short8* wp8 = (const short8*)wout;
  const int t = threadIdx.x, wid = t >> 6, lane = t & 63;
  const int q0 = blockIdx.x * 64;
  const int g = lane >> 4, l15 = lane & 15;
  const f32x4 z4 = {0.f, 0.f, 0.f, 0.f};
  f32x4 acc[4][4];
#pragma unroll
  for (int i = 0; i < 4; ++i)
#pragma unroll
    for (int j = 0; j < 4; ++j) acc[i][j] = z4;

  // stage ks=0: wave wid stages chunks gg=wid, q=lane (1 issue/wave)
  gload_lds16(S + ((size_t)(q0 + lane) * 256 + wid * 8), smem + wid * 1024);
  __syncthreads();

#pragma unroll
  for (int ks = 0; ks < 8; ++ks) {
    if (ks < 7)
      gload_lds16(S + ((size_t)(q0 + lane) * 256 + (ks + 1) * 32 + wid * 8),
                  smem + (((ks + 1) & 1) ? 4096 : 0) + wid * 1024);
    short8 af[4];
#pragma unroll
    for (int df = 0; df < 4; ++df)
      af[df] = wp8[(ks * 4 + g) * 256 + wid * 64 + df * 16 + l15];
    short8 bf[4];
    const short8* sb = lds8 + ((ks & 1) ? 256 : 0);
#pragma unroll
    for (int qf = 0; qf < 4; ++qf) bf[qf] = sb[g * 64 + qf * 16 + l15];
#pragma unroll
    for (int df = 0; df < 4; ++df)
#pragma unroll
      for (int qf = 0; qf < 4; ++qf)
        acc[df][qf] = __builtin_amdgcn_mfma_f32_16x16x32_bf16(af[df], bf[qf], acc[df][qf], 0, 0, 0);
    __syncthreads();
  }

#pragma unroll
  for (int df = 0; df < 4; ++df) {
    const int db = wid * 64 + df * 16 + g * 4;
    const float4 ob4 = *(const float4*)(out_b + db);
#pragma unroll
    for (int qf = 0; qf < 4; ++qf) {
      const int q = q0 + qf * 16 + l15;
      const float4 qv = *(const float4*)(queries + (size_t)q * 256 + db);
      float4 ov;
      ov.x = acc[df][qf][0] + ob4.x + qv.x;
      ov.y = acc[df][qf][1] + ob4.y + qv.y;
      ov.z = acc[df][qf][2] + ob4.z + qv.z;
      ov.w = acc[df][qf][3] + ob4.w + qv.w;
      *(float4*)(out + (size_t)q * 256 + db) = ov;
    }
  }
}

// ---------------------------------------------------------------------------
extern "C" void kernel_launch(void* const* d_in, const int* in_sizes, int n_in,
                              void* d_out, int out_size, void* d_ws, size_t ws_size,
                              hipStream_t stream) {
  const float* queries = (const float*)d_in[0];
  const float* traj    = (const float*)d_in[1];
  const float* bev     = (const float*)d_in[2];
  const float* attn_w  = (const float*)d_in[4];
  const float* attn_b  = (const float*)d_in[5];
  const float* conv_w  = (const float*)d_in[6];
  const float* conv_b  = (const float*)d_in[7];
  const float* out_w   = (const float*)d_in[8];
  const float* out_b   = (const float*)d_in[9];
  float* out = (float*)d_out;

  char* ws = (char*)d_ws;
  unsigned short* bev_nhwc = (unsigned short*)(ws);               //  33,554,432 B
  unsigned short* value    = (unsigned short*)(ws + 33554432);    // 134,217,728 B
  unsigned short* wconv    = (unsigned short*)(ws + 167772160);   //     294,912 B
  unsigned short* wout     = (unsigned short*)(ws + 168067072);   //     131,072 B
  unsigned short* Sbuf     = (unsigned short*)(ws + 168198144);   //   8,388,608 B
  float*          zp       = (float*)(ws + 176586752);            //         256 B

  k1_transpose<<<2048, 256, 0, stream>>>(bev, bev_nhwc);
  k1b_pack<<<64, 256, 0, stream>>>(conv_w, out_w, wconv, wout, zp);
  k2_conv<<<1024, 512, 0, stream>>>(bev_nhwc, wconv, conv_b, zp, value);
  k3_sample<<<4096, 256, 0, stream>>>(queries, traj, attn_w, attn_b, value, Sbuf);
  k4_proj<<<256, 256, 0, stream>>>(Sbuf, wout, out_b, queries, out);
}

// Round 8
// 158.226 us; speedup vs baseline: 1.1636x; 1.0141x over previous
//
#include <hip/hip_runtime.h>
#include <stdint.h>

// Problem constants: bs=16, Q=1024, P=8, D=256, Cin=64, H=W=128, Cout=256.

typedef __attribute__((ext_vector_type(8))) short short8;   // 8 bf16 (4 VGPR)
typedef __attribute__((ext_vector_type(4))) float f32x4;    // MFMA acc

__device__ __forceinline__ unsigned short f2bf(float f) {
  union { float f; unsigned int u; } v; v.f = f;
  unsigned int r = (v.u + 0x7FFFu + ((v.u >> 16) & 1u)) >> 16;  // RNE
  return (unsigned short)r;
}
__device__ __forceinline__ float bf2f(unsigned short h) {
  union { unsigned int u; float f; } v; v.u = ((unsigned int)h) << 16;
  return v.f;
}

// async global->LDS, 16B per lane; LDS dest wave-uniform (HW adds lane*16),
// global src per-lane.
__device__ __forceinline__ void gload_lds16(const void* g, void* l) {
  __builtin_amdgcn_global_load_lds(
      (const __attribute__((address_space(1))) unsigned int*)g,
      (__attribute__((address_space(3))) unsigned int*)l, 16, 0, 0);
}

// ---------------------------------------------------------------------------
// K1: bev (16,64,128,128) f32 NCHW -> bev_nhwc (16,128,128,64) bf16 (unchanged)
// ---------------------------------------------------------------------------
__global__ __launch_bounds__(256) void k1_transpose(const float* __restrict__ bev,
                                                    unsigned short* __restrict__ nhwc) {
  __shared__ __align__(16) float lds[64 * 32 * 4];
  const int b = blockIdx.x >> 7, y = blockIdx.x & 127;
  const int t = threadIdx.x;
  const float* src = bev + (size_t)(b * 64) * 16384 + y * 128;
#pragma unroll
  for (int k = 0; k < 8; ++k) {
    int chunk = k * 256 + t;
    int ic = chunk >> 5, xq = chunk & 31;
    float4 v = *(const float4*)(src + ic * 16384 + xq * 4);
    int slot = xq ^ (ic >> 3);
    *(float4*)&lds[(ic * 32 + slot) * 4] = v;
  }
  __syncthreads();
  unsigned short* dst = nhwc + (size_t)blockIdx.x * 8192;
#pragma unroll
  for (int k = 0; k < 4; ++k) {
    int co = k * 256 + t;
    int x = co >> 3, icg = co & 7;
    int slot = (x >> 2) ^ icg;
    int w = x & 3;
    uint4 u;
    unsigned int* up = (unsigned int*)&u;
#pragma unroll
    for (int jj = 0; jj < 4; ++jj) {
      float v0 = lds[((icg * 8 + 2 * jj) * 32 + slot) * 4 + w];
      float v1 = lds[((icg * 8 + 2 * jj + 1) * 32 + slot) * 4 + w];
      up[jj] = (unsigned int)f2bf(v0) | ((unsigned int)f2bf(v1) << 16);
    }
    *(uint4*)(dst + x * 64 + icg * 8) = u;
  }
}

// ---------------------------------------------------------------------------
// K1b: pack weights (unchanged layouts)
//   wconv[o][gg8][oc256][j8] = conv_w[oc][gg*8+j][o/3][o%3]
//   wout [cg32][d256][j8]    = out_w[d][cg*8+j]
// ---------------------------------------------------------------------------
__global__ __launch_bounds__(256) void k1b_pack(const float* __restrict__ conv_w,
                                                const float* __restrict__ out_w,
                                                unsigned short* __restrict__ wconv,
                                                unsigned short* __restrict__ wout,
                                                float* __restrict__ zp) {
  const int tid = blockIdx.x * 256 + threadIdx.x;
  for (int idx = tid; idx < 9 * 8 * 256 * 8; idx += 16384) {
    int j = idx & 7, oc = (idx >> 3) & 255, g = (idx >> 11) & 7, o = idx >> 14;
    wconv[idx] = f2bf(conv_w[(oc * 64 + g * 8 + j) * 9 + o]);
  }
  for (int idx = tid; idx < 32 * 256 * 8; idx += 16384) {
    int j = idx & 7, d = (idx >> 3) & 255, g = idx >> 11;
    wout[idx] = f2bf(out_w[d * 256 + g * 8 + j]);
  }
  if (tid < 64) zp[tid] = 0.0f;
}

// ---------------------------------------------------------------------------
// K2 v8: 3x3 conv + bias + relu, implicit GEMM, D[oc][pix] = W[oc][k]·In[k][pix]
// Barrier-free K-loop (v6/v7 structure) at BLOCK granularity for desync:
// 2048 blocks x 256 thr; block = (b,y) one row, 128 pix x 256 oc.
// 4 waves = 4 distinct oc-quarters (NO A redundancy), wave 64oc x 128pix,
// acc[4][8]=128 AGPR. Two independent blocks co-resident per CU -> their
// waves interleave stalls (m114 block-level overlap) without shared barriers.
// A: 4 global loads/wave/step from L2-resident wconv, dbuf, prefetch dist 2.
// B: 8 ds_read_b128/wave/step from read-only 3-row halo (48.75KB + pad).
// Epilogue: pf-outer store order (groups same-pixel-line writes).
// ---------------------------------------------------------------------------
#define K2_LOADA(s, A) do {                                                   \
    _Pragma("unroll")                                                         \
    for (int ocf_ = 0; ocf_ < 4; ++ocf_)                                      \
      A[ocf_] = gA[(4 * (s) + g) * 256 + wo * 64 + ocf_ * 16 + l15];          \
  } while (0)

#define K2_READB(s, h, B) do {                                                \
    const int o_ = (s) >> 1, ich_ = (s) & 1;                                  \
    const int dyr_ = o_ / 3, dx_ = o_ - dyr_ * 3 - 1;                         \
    _Pragma("unroll")                                                         \
    for (int pf_ = 0; pf_ < 4; ++pf_)                                         \
      B[pf_] = lin[(dyr_ * 8 + ich_ * 4 + g) * 130 + 1 + dx_ +                \
                   ((h) * 4 + pf_) * 16 + l15];                               \
  } while (0)

#define K2_MF(A, B, h) do {                                                   \
    _Pragma("unroll")                                                         \
    for (int ocf_ = 0; ocf_ < 4; ++ocf_)                                      \
      _Pragma("unroll")                                                       \
      for (int pf_ = 0; pf_ < 4; ++pf_)                                       \
        acc[ocf_][(h) * 4 + pf_] = __builtin_amdgcn_mfma_f32_16x16x32_bf16(   \
            A[ocf_], B[pf_], acc[ocf_][(h) * 4 + pf_], 0, 0, 0);              \
  } while (0)

__global__ __launch_bounds__(256, 2) void k2_conv(const unsigned short* __restrict__ nhwc,
                                                  const unsigned short* __restrict__ wconv,
                                                  const float* __restrict__ conv_b,
                                                  const float* __restrict__ zp,
                                                  unsigned short* __restrict__ value) {
  __shared__ __align__(16) char smem[50176];     // 3-row halo 49,920B + pad
  const short8* lin = (const short8*)smem;
  const short8* gA = (const short8*)wconv;
  const int bid = blockIdx.x;
  const int swz = (bid & 7) * 256 + (bid >> 3);    // XCD swizzle: 2 images/XCD
  const int b = swz >> 7, y = swz & 127;
  const int t = threadIdx.x, wid = t >> 6, lane = t & 63;
  const int wo = wid;                              // oc-quarter
  const int g = lane >> 4, l15 = lane & 15;

  // ---- prologue: stage input rows y-1..y+1 (3120 chunks = 49 issues) ----
  const unsigned short* bevb = nhwc + (size_t)b * (128 * 128 * 64);
  for (int i = wid; i < 49; i += 4) {
    const int chunk = i * 64 + lane;
    const void* src = (const void*)zp;
    if (chunk < 3120) {
      const int ridx = chunk / 1040;
      const int rem = chunk - ridx * 1040;
      const int icg = rem / 130;
      const int c = rem - icg * 130;
      const int yy = y - 1 + ridx, xx = c - 1;
      if (yy >= 0 && yy < 128 && xx >= 0 && xx < 128)
        src = (const void*)(bevb + ((yy * 128 + xx) * 64 + icg * 8));
    }
    gload_lds16(src, smem + i * 1024);             // issue 48 tail pads into smem[49152..]
  }
  __syncthreads();   // drains gload_lds (vmcnt0) + barrier; LDS read-only after

  const f32x4 z4 = {0.f, 0.f, 0.f, 0.f};
  f32x4 acc[4][8];
#pragma unroll
  for (int i = 0; i < 4; ++i)
#pragma unroll
    for (int j = 0; j < 8; ++j) acc[i][j] = z4;

  short8 A0[4], A1[4], B0[4], B1[4];
  K2_LOADA(0, A0);
  K2_LOADA(1, A1);

#pragma unroll
  for (int s = 0; s < 18; ++s) {
    K2_READB(s, 0, B0);                             // LDS reads for this step
    K2_READB(s, 1, B1);
    if (s & 1) {
      K2_MF(A1, B0, 0);
      K2_MF(A1, B1, 1);
      if (s + 2 < 18) K2_LOADA(s + 2, A1);          // global prefetch dist-2
    } else {
      K2_MF(A0, B0, 0);
      K2_MF(A0, B1, 1);
      if (s + 2 < 18) K2_LOADA(s + 2, A0);
    }
  }

  // ---- epilogue: bias + relu; pf-outer store order for write coalescing ----
  unsigned short* vrow = value + (((size_t)(b * 128 + y) * 128 + l15) * 256);
  float4 cb4[4];
#pragma unroll
  for (int ocf = 0; ocf < 4; ++ocf)
    cb4[ocf] = *(const float4*)(conv_b + wo * 64 + ocf * 16 + g * 4);
#pragma unroll
  for (int pf = 0; pf < 8; ++pf) {
#pragma unroll
    for (int ocf = 0; ocf < 4; ++ocf) {
      const int ocb = wo * 64 + ocf * 16 + g * 4;
      ushort4 ov;
      float v0 = acc[ocf][pf][0] + cb4[ocf].x; ov.x = f2bf(v0 > 0.f ? v0 : 0.f);
      float v1 = acc[ocf][pf][1] + cb4[ocf].y; ov.y = f2bf(v1 > 0.f ? v1 : 0.f);
      float v2 = acc[ocf][pf][2] + cb4[ocf].z; ov.z = f2bf(v2 > 0.f ? v2 : 0.f);
      float v3 = acc[ocf][pf][3] + cb4[ocf].w; ov.w = f2bf(v3 > 0.f ? v3 : 0.f);
      *(ushort4*)(vrow + (size_t)pf * 16 * 256 + ocb) = ov;
    }
  }
}

// ---------------------------------------------------------------------------
// K3: per-query softmax + bilinear grid-sample + P-weighted sum (unchanged)
// ---------------------------------------------------------------------------
__global__ __launch_bounds__(256) void k3_sample(const float* __restrict__ queries,
                                                 const float* __restrict__ traj,
                                                 const float* __restrict__ attn_w,
                                                 const float* __restrict__ attn_b,
                                                 const unsigned short* __restrict__ value,
                                                 unsigned short* __restrict__ S) {
  const int wid = threadIdx.x >> 6, lane = threadIdx.x & 63;
  const int qg = blockIdx.x * 4 + wid;
  const int b = qg >> 10;
  const float4 qv = ((const float4*)queries)[qg * 64 + lane];
  float a[8];
#pragma unroll
  for (int p = 0; p < 8; ++p) {
    float4 wv = ((const float4*)attn_w)[p * 64 + lane];
    float d = qv.x * wv.x + qv.y * wv.y + qv.z * wv.z + qv.w * wv.w;
#pragma unroll
    for (int off = 32; off >= 1; off >>= 1) d += __shfl_xor(d, off);
    a[p] = d + attn_b[p];
  }
  float mx = a[0];
#pragma unroll
  for (int p = 1; p < 8; ++p) mx = fmaxf(mx, a[p]);
  float ssum = 0.f;
#pragma unroll
  for (int p = 0; p < 8; ++p) { a[p] = __expf(a[p] - mx); ssum += a[p]; }
  const float inv = 1.f / ssum;

  float acc0 = 0.f, acc1 = 0.f, acc2 = 0.f, acc3 = 0.f;
  const unsigned short* vb = value + (size_t)b * (128 * 128 * 256);
  const int coff = lane * 4;
#pragma unroll
  for (int p = 0; p < 8; ++p) {
    const float ty = traj[(qg * 8 + p) * 2 + 0];
    const float tx = traj[(qg * 8 + p) * 2 + 1];
    const float fx = (tx * 0.03125f + 1.f) * 64.f - 0.5f;
    const float fy = (ty * 0.03125f + 1.f) * 64.f - 0.5f;
    const float fx0 = floorf(fx), fy0 = floorf(fy);
    const int ix0 = (int)fx0, iy0 = (int)fy0;
    const float wx1 = fx - fx0, wx0 = 1.f - wx1;
    const float wy1 = fy - fy0, wy0 = 1.f - wy1;
    const float ap = a[p] * inv;
    const float cw[4] = {wx0 * wy0 * ap, wx1 * wy0 * ap, wx0 * wy1 * ap, wx1 * wy1 * ap};
    const int cx[4] = {ix0, ix0 + 1, ix0, ix0 + 1};
    const int cy[4] = {iy0, iy0, iy0 + 1, iy0 + 1};
#pragma unroll
    for (int cc = 0; cc < 4; ++cc) {
      if (cx[cc] >= 0 && cx[cc] < 128 && cy[cc] >= 0 && cy[cc] < 128) {
        const ushort4 v = *(const ushort4*)(vb + (cy[cc] * 128 + cx[cc]) * 256 + coff);
        acc0 += cw[cc] * bf2f(v.x);
        acc1 += cw[cc] * bf2f(v.y);
        acc2 += cw[cc] * bf2f(v.z);
        acc3 += cw[cc] * bf2f(v.w);
      }
    }
  }
  ushort4 o;
  o.x = f2bf(acc0); o.y = f2bf(acc1); o.z = f2bf(acc2); o.w = f2bf(acc3);
  *(ushort4*)(S + (size_t)qg * 256 + coff) = o;
}

// ---------------------------------------------------------------------------
// K4 v3: out[q][d] = S[q][:] . out_w[d][:] + out_b[d] + queries[q][d]
// (unchanged from round 7)
// ---------------------------------------------------------------------------
__global__ __launch_bounds__(256, 2) void k4_proj(const unsigned short* __restrict__ S,
                                                  const unsigned short* __restrict__ wout,
                                                  const float* __restrict__ out_b,
                                                  const float* __restrict__ queries,
                                                  float* __restrict__ out) {
  __shared__ __align__(16) char smem[8192];      // 2 x 256 chunks [gg4][q64]
  const short8* lds8 = (const short8*)smem;
  const short8* wp8 = (const short8*)wout;
  const int t = threadIdx.x, wid = t >> 6, lane = t & 63;
  const int q0 = blockIdx.x * 64;
  const int g = lane >> 4, l15 = lane & 15;
  const f32x4 z4 = {0.f, 0.f, 0.f, 0.f};
  f32x4 acc[4][4];
#pragma unroll
  for (int i = 0; i < 4; ++i)
#pragma unroll
    for (int j = 0; j < 4; ++j) acc[i][j] = z4;

  // stage ks=0: wave wid stages chunks gg=wid, q=lane (1 issue/wave)
  gload_lds16(S + ((size_t)(q0 + lane) * 256 + wid * 8), smem + wid * 1024);
  __syncthreads();

#pragma unroll
  for (int ks = 0; ks < 8; ++ks) {
    if (ks < 7)
      gload_lds16(S + ((size_t)(q0 + lane) * 256 + (ks + 1) * 32 + wid * 8),
                  smem + (((ks + 1) & 1) ? 4096 : 0) + wid * 1024);
    short8 af[4];
#pragma unroll
    for (int df = 0; df < 4; ++df)
      af[df] = wp8[(ks * 4 + g) * 256 + wid * 64 + df * 16 + l15];
    short8 bf[4];
    const short8* sb = lds8 + ((ks & 1) ? 256 : 0);
#pragma unroll
    for (int qf = 0; qf < 4; ++qf) bf[qf] = sb[g * 64 + qf * 16 + l15];
#pragma unroll
    for (int df = 0; df < 4; ++df)
#pragma unroll
      for (int qf = 0; qf < 4; ++qf)
        acc[df][qf] = __builtin_amdgcn_mfma_f32_16x16x32_bf16(af[df], bf[qf], acc[df][qf], 0, 0, 0);
    __syncthreads();
  }

#pragma unroll
  for (int df = 0; df < 4; ++df) {
    const int db = wid * 64 + df * 16 + g * 4;
    const float4 ob4 = *(const float4*)(out_b + db);
#pragma unroll
    for (int qf = 0; qf < 4; ++qf) {
      const int q = q0 + qf * 16 + l15;
      const float4 qv = *(const float4*)(queries + (size_t)q * 256 + db);
      float4 ov;
      ov.x = acc[df][qf][0] + ob4.x + qv.x;
      ov.y = acc[df][qf][1] + ob4.y + qv.y;
      ov.z = acc[df][qf][2] + ob4.z + qv.z;
      ov.w = acc[df][qf][3] + ob4.w + qv.w;
      *(float4*)(out + (size_t)q * 256 + db) = ov;
    }
  }
}

// ---------------------------------------------------------------------------
extern "C" void kernel_launch(void* const* d_in, const int* in_sizes, int n_in,
                              void* d_out, int out_size, void* d_ws, size_t ws_size,
                              hipStream_t stream) {
  const float* queries = (const float*)d_in[0];
  const float* traj    = (const float*)d_in[1];
  const float* bev     = (const float*)d_in[2];
  const float* attn_w  = (const float*)d_in[4];
  const float* attn_b  = (const float*)d_in[5];
  const float* conv_w  = (const float*)d_in[6];
  const float* conv_b  = (const float*)d_in[7];
  const float* out_w   = (const float*)d_in[8];
  const float* out_b   = (const float*)d_in[9];
  float* out = (float*)d_out;

  char* ws = (char*)d_ws;
  unsigned short* bev_nhwc = (unsigned short*)(ws);               //  33,554,432 B
  unsigned short* value    = (unsigned short*)(ws + 33554432);    // 134,217,728 B
  unsigned short* wconv    = (unsigned short*)(ws + 167772160);   //     294,912 B
  unsigned short* wout     = (unsigned short*)(ws + 168067072);   //     131,072 B
  unsigned short* Sbuf     = (unsigned short*)(ws + 168198144);   //   8,388,608 B
  float*          zp       = (float*)(ws + 176586752);            //         256 B

  k1_transpose<<<2048, 256, 0, stream>>>(bev, bev_nhwc);
  k1b_pack<<<64, 256, 0, stream>>>(conv_w, out_w, wconv, wout, zp);
  k2_conv<<<2048, 256, 0, stream>>>(bev_nhwc, wconv, conv_b, zp, value);
  k3_sample<<<4096, 256, 0, stream>>>(queries, traj, attn_w, attn_b, value, Sbuf);
  k4_proj<<<256, 256, 0, stream>>>(Sbuf, wout, out_b, queries, out);
}